// Round 1
// baseline (590.227 us; speedup 1.0000x reference)
//
#include <hip/hip_runtime.h>
#include <hip/hip_bf16.h>
#include <math.h>

// Problem constants (from reference): N=50000, E=800000, D_IN=64, D_HID=128, D_OUT=64

// ---------------------------------------------------------------------------
// K1: degree count + scatter-sum of x rows (64 ch) into agg1. 64 threads/edge.
__global__ __launch_bounds__(256) void scatter1_kernel(
    const float* __restrict__ x, const int* __restrict__ src,
    const int* __restrict__ dst, float* __restrict__ agg,
    float* __restrict__ deg, int E)
{
    int t = blockIdx.x * 256 + threadIdx.x;
    int e = t >> 6, c = t & 63;
    if (e >= E) return;
    int s = src[e], d = dst[e];
    atomicAdd(&agg[(size_t)d * 64 + c], x[(size_t)s * 64 + c]);
    if (c == 0) atomicAdd(&deg[d], 1.0f);
}

// K4: scatter-sum of m2 rows (64 ch) into agg2.
__global__ __launch_bounds__(256) void scatter2_kernel(
    const float* __restrict__ m2, const int* __restrict__ src,
    const int* __restrict__ dst, float* __restrict__ agg, int E)
{
    int t = blockIdx.x * 256 + threadIdx.x;
    int e = t >> 6, c = t & 63;
    if (e >= E) return;
    int s = src[e], d = dst[e];
    atomicAdd(&agg[(size_t)d * 64 + c], m2[(size_t)s * 64 + c]);
}

// ---------------------------------------------------------------------------
// K2: h[n] = tanh( (agg1[n]/max(deg,1)) @ Wl1^T + b1 + x[n] @ Wr1^T )
// Wl1, Wr1: [128][64] row-major. 16 nodes/block, 256 threads, 8 outs/thread.
#define NPB 16
__global__ __launch_bounds__(256) void layer1_kernel(
    const float* __restrict__ x, const float* __restrict__ agg,
    const float* __restrict__ deg, const float* __restrict__ Wl,
    const float* __restrict__ bl, const float* __restrict__ Wr,
    float* __restrict__ h, int nNodes)
{
    __shared__ float sWl[128][68];   // pad 64->68: 16B-aligned rows, bank-shifted
    __shared__ float sWr[128][68];
    __shared__ float sx[NPB][68];
    __shared__ float sa[NPB][68];
    int tid = threadIdx.x;

    // Stage weights: 128*16 float4 per matrix, 256 threads.
    for (int i = tid; i < 128 * 16; i += 256) {
        int r = i >> 4, c4 = i & 15;
        *(float4*)&sWl[r][c4 * 4] = ((const float4*)Wl)[i];
        *(float4*)&sWr[r][c4 * 4] = ((const float4*)Wr)[i];
    }
    int node0 = blockIdx.x * NPB;
    {   // Stage 16 node rows of x and agg/deg (pre-divided).
        int r = tid >> 4, c4 = tid & 15;
        int n = node0 + r;
        float4 xv = make_float4(0.f, 0.f, 0.f, 0.f), av = xv;
        float dg = 1.f;
        if (n < nNodes) {
            xv = ((const float4*)(x + (size_t)n * 64))[c4];
            av = ((const float4*)(agg + (size_t)n * 64))[c4];
            dg = deg[n];
            if (dg < 1.f) dg = 1.f;
        }
        float inv = 1.f / dg;
        av.x *= inv; av.y *= inv; av.z *= inv; av.w *= inv;
        *(float4*)&sx[r][c4 * 4] = xv;
        *(float4*)&sa[r][c4 * 4] = av;
    }
    __syncthreads();

    int n  = tid & (NPB - 1);
    int o0 = (tid >> 4) * 8;
    float acc[8];
#pragma unroll
    for (int j = 0; j < 8; j++) acc[j] = bl[o0 + j];
    for (int k4 = 0; k4 < 16; k4++) {
        float4 xv = *(const float4*)&sx[n][k4 * 4];
        float4 av = *(const float4*)&sa[n][k4 * 4];
#pragma unroll
        for (int j = 0; j < 8; j++) {
            float4 wr = *(const float4*)&sWr[o0 + j][k4 * 4];
            float4 wl = *(const float4*)&sWl[o0 + j][k4 * 4];
            acc[j] += xv.x * wr.x + xv.y * wr.y + xv.z * wr.z + xv.w * wr.w
                    + av.x * wl.x + av.y * wl.y + av.z * wl.z + av.w * wl.w;
        }
    }
    int gn = node0 + n;
    if (gn < nNodes) {
#pragma unroll
        for (int j = 0; j < 8; j++)
            h[(size_t)gn * 128 + o0 + j] = tanhf(acc[j]);
    }
}

// ---------------------------------------------------------------------------
// K3: m2[n] = h[n] @ Wl2^T ; r2[n] = h[n] @ Wr2^T + b2  (both 64-wide)
// Wl2, Wr2: [64][128] row-major. Concatenate into 128 virtual output rows.
__global__ __launch_bounds__(256) void layer2a_kernel(
    const float* __restrict__ h, const float* __restrict__ Wl2,
    const float* __restrict__ bl2, const float* __restrict__ Wr2,
    float* __restrict__ m2, float* __restrict__ r2, int nNodes)
{
    __shared__ float sW[128][132];   // rows 0..63 = Wl2, 64..127 = Wr2 (pad 128->132)
    __shared__ float sh[16][132];
    int tid = threadIdx.x;

    for (int i = tid; i < 64 * 32; i += 256) {   // 2048 float4 per matrix
        int r = i >> 5, c4 = i & 31;
        *(float4*)&sW[r][c4 * 4]      = ((const float4*)Wl2)[i];
        *(float4*)&sW[r + 64][c4 * 4] = ((const float4*)Wr2)[i];
    }
    int node0 = blockIdx.x * 16;
    for (int i = tid; i < 16 * 32; i += 256) {
        int r = i >> 5, c4 = i & 31;
        int n = node0 + r;
        float4 v = make_float4(0.f, 0.f, 0.f, 0.f);
        if (n < nNodes) v = ((const float4*)(h + (size_t)n * 128))[c4];
        *(float4*)&sh[r][c4 * 4] = v;
    }
    __syncthreads();

    int n  = tid & 15;
    int o0 = (tid >> 4) * 8;
    float acc[8];
#pragma unroll
    for (int j = 0; j < 8; j++)
        acc[j] = (o0 + j >= 64) ? bl2[o0 + j - 64] : 0.f;
    for (int k4 = 0; k4 < 32; k4++) {
        float4 hv = *(const float4*)&sh[n][k4 * 4];
#pragma unroll
        for (int j = 0; j < 8; j++) {
            float4 w = *(const float4*)&sW[o0 + j][k4 * 4];
            acc[j] += hv.x * w.x + hv.y * w.y + hv.z * w.z + hv.w * w.w;
        }
    }
    int gn = node0 + n;
    if (gn < nNodes) {
        if (o0 < 64) {
#pragma unroll
            for (int j = 0; j < 8; j++) m2[(size_t)gn * 64 + o0 + j] = acc[j];
        } else {
#pragma unroll
            for (int j = 0; j < 8; j++) r2[(size_t)gn * 64 + (o0 - 64) + j] = acc[j];
        }
    }
}

// ---------------------------------------------------------------------------
// K5: out[n] = log_softmax( agg2[n]/max(deg,1) + r2[n] ), one node per wave.
__global__ __launch_bounds__(256) void final_kernel(
    const float* __restrict__ agg2, const float* __restrict__ deg,
    float* __restrict__ out, int nNodes)
{
    int t = blockIdx.x * 256 + threadIdx.x;
    int n = t >> 6, c = t & 63;
    if (n >= nNodes) return;
    float dg = deg[n];
    if (dg < 1.f) dg = 1.f;
    float v = agg2[(size_t)n * 64 + c] / dg + out[(size_t)n * 64 + c];
    float m = v;
#pragma unroll
    for (int off = 32; off; off >>= 1) m = fmaxf(m, __shfl_xor(m, off, 64));
    float ex = expf(v - m);
    float s = ex;
#pragma unroll
    for (int off = 32; off; off >>= 1) s += __shfl_xor(s, off, 64);
    out[(size_t)n * 64 + c] = (v - m) - logf(s);
}

// ---------------------------------------------------------------------------
extern "C" void kernel_launch(void* const* d_in, const int* in_sizes, int n_in,
                              void* d_out, int out_size, void* d_ws, size_t ws_size,
                              hipStream_t stream)
{
    const float* x   = (const float*)d_in[0];
    const int*   ei  = (const int*)d_in[1];
    const float* Wl1 = (const float*)d_in[2];
    const float* bl1 = (const float*)d_in[3];
    const float* Wr1 = (const float*)d_in[4];
    const float* Wl2 = (const float*)d_in[5];
    const float* bl2 = (const float*)d_in[6];
    const float* Wr2 = (const float*)d_in[7];
    float* out = (float*)d_out;

    int N = in_sizes[0] / 64;   // 50000
    int E = in_sizes[1] / 2;    // 800000
    const int* src = ei;
    const int* dst = ei + E;

    float* ws   = (float*)d_ws;
    size_t npad = ((size_t)N + 63) & ~(size_t)63;
    float* deg  = ws;                        // [N]
    float* a64  = ws + npad;                 // [N*64]  agg1, then reused as m2
    float* h    = a64 + (size_t)N * 64;      // [N*128]
    float* agg2 = h + (size_t)N * 128;       // [N*64]

    // Zero the accumulators (harness poisons d_ws each launch).
    hipMemsetAsync(deg,  0, (size_t)N * sizeof(float), stream);
    hipMemsetAsync(a64,  0, (size_t)N * 64 * sizeof(float), stream);
    hipMemsetAsync(agg2, 0, (size_t)N * 64 * sizeof(float), stream);

    // Phase 1: degree + scatter-sum(x) -> agg1
    {
        int blocks = (E * 64 + 255) / 256;
        scatter1_kernel<<<blocks, 256, 0, stream>>>(x, src, dst, a64, deg, E);
    }
    // Phase 2: h = tanh(agg1/deg @ Wl1^T + b1 + x @ Wr1^T)
    {
        int blocks = (N + NPB - 1) / NPB;
        layer1_kernel<<<blocks, 256, 0, stream>>>(x, a64, deg, Wl1, bl1, Wr1, h, N);
    }
    // Phase 3: m2 = h @ Wl2^T (into a64), r2 = h @ Wr2^T + b2 (into d_out)
    {
        int blocks = (N + 15) / 16;
        layer2a_kernel<<<blocks, 256, 0, stream>>>(h, Wl2, bl2, Wr2, a64, out, N);
    }
    // Phase 4: scatter-sum(m2) -> agg2
    {
        int blocks = (E * 64 + 255) / 256;
        scatter2_kernel<<<blocks, 256, 0, stream>>>(a64, src, dst, agg2, E);
    }
    // Phase 5: out = log_softmax(agg2/deg + r2)
    {
        int blocks = (N * 64 + 255) / 256;
        final_kernel<<<blocks, 256, 0, stream>>>(agg2, deg, out, N);
    }
}

// Round 2
// 432.801 us; speedup vs baseline: 1.3637x; 1.3637x over previous
//
#include <hip/hip_runtime.h>
#include <hip/hip_bf16.h>
#include <math.h>

// N=50000, E=800000, D_IN=64, D_HID=128, D_OUT=64
// Pipeline: CSR build (count/scan/fill) -> gather1 -> layer1 -> layer2 ->
//           fused gather2+log_softmax. Scatter atomics eliminated.

// ---------------------------------------------------------------------------
// CSR build step 1: histogram of dst.
__global__ __launch_bounds__(256) void count_kernel(
    const int* __restrict__ dst, int* __restrict__ cnt, int E)
{
    int e = blockIdx.x * 256 + threadIdx.x;
    if (e < E) atomicAdd(&cnt[dst[e]], 1);
}

// CSR build step 2: exclusive scan of cnt -> off[0..N], cur[0..N-1]=off copy.
// Single block, 1024 threads, each thread owns a contiguous range.
__global__ __launch_bounds__(1024) void scan_kernel(
    const int* __restrict__ cnt, int* __restrict__ off,
    int* __restrict__ cur, int n)
{
    __shared__ int ssum[1024];
    int t = threadIdx.x;
    int R = (n + 1023) / 1024;
    int lo = t * R;
    int hi = min(lo + R, n);
    int s = 0;
    for (int i = lo; i < hi; i++) s += cnt[i];
    ssum[t] = s;
    __syncthreads();
    // Hillis-Steele inclusive scan over 1024 entries.
    for (int d = 1; d < 1024; d <<= 1) {
        int v = (t >= d) ? ssum[t - d] : 0;
        __syncthreads();
        ssum[t] += v;
        __syncthreads();
    }
    int run = (t == 0) ? 0 : ssum[t - 1];
    for (int i = lo; i < hi; i++) {
        off[i] = run; cur[i] = run;
        run += cnt[i];
    }
    if (hi == n) off[n] = run;   // all writers write the same value (=E)
}

// CSR build step 3: bucket src indices by dst via atomic ticket.
__global__ __launch_bounds__(256) void fill_kernel(
    const int* __restrict__ src, const int* __restrict__ dst,
    int* __restrict__ cur, int* __restrict__ perm, int E)
{
    int e = blockIdx.x * 256 + threadIdx.x;
    if (e >= E) return;
    int pos = atomicAdd(&cur[dst[e]], 1);
    perm[pos] = src[e];
}

// ---------------------------------------------------------------------------
// Wave-cooperative row gather-sum: lane = channel (64), rows = feat[idx*64..].
__device__ __forceinline__ float gather_row_sum(
    const float* __restrict__ feat, const int* __restrict__ perm,
    int lo, int hi, int lane)
{
    float a0 = 0.f, a1 = 0.f, a2 = 0.f, a3 = 0.f;
    for (int base = lo; base < hi; base += 64) {
        int cnt = min(64, hi - base);
        int pidx = (lane < cnt) ? perm[base + lane] : 0;
        int j = 0;
        for (; j + 4 <= cnt; j += 4) {
            int i0 = __shfl(pidx, j,     64);
            int i1 = __shfl(pidx, j + 1, 64);
            int i2 = __shfl(pidx, j + 2, 64);
            int i3 = __shfl(pidx, j + 3, 64);
            a0 += feat[(size_t)i0 * 64 + lane];
            a1 += feat[(size_t)i1 * 64 + lane];
            a2 += feat[(size_t)i2 * 64 + lane];
            a3 += feat[(size_t)i3 * 64 + lane];
        }
        for (; j < cnt; j++) {
            int i0 = __shfl(pidx, j, 64);
            a0 += feat[(size_t)i0 * 64 + lane];
        }
    }
    return (a0 + a1) + (a2 + a3);
}

// Phase A: agg1[n] = mean of x[src] over n's in-edges (pre-divided).
__global__ __launch_bounds__(256) void gather1_kernel(
    const float* __restrict__ x, const int* __restrict__ perm,
    const int* __restrict__ off, float* __restrict__ agg, int N)
{
    int wid  = (blockIdx.x * 256 + threadIdx.x) >> 6;
    int lane = threadIdx.x & 63;
    if (wid >= N) return;
    int lo = off[wid], hi = off[wid + 1];
    float s = gather_row_sum(x, perm, lo, hi, lane);
    float inv = 1.f / fmaxf((float)(hi - lo), 1.f);
    agg[(size_t)wid * 64 + lane] = s * inv;
}

// ---------------------------------------------------------------------------
// K2: h[n] = tanh( agg[n] @ Wl1^T + b1 + x[n] @ Wr1^T ); agg pre-divided.
#define NPB 16
__global__ __launch_bounds__(256) void layer1_kernel(
    const float* __restrict__ x, const float* __restrict__ agg,
    const float* __restrict__ Wl, const float* __restrict__ bl,
    const float* __restrict__ Wr, float* __restrict__ h, int nNodes)
{
    __shared__ float sWl[128][68];
    __shared__ float sWr[128][68];
    __shared__ float sx[NPB][68];
    __shared__ float sa[NPB][68];
    int tid = threadIdx.x;

    for (int i = tid; i < 128 * 16; i += 256) {
        int r = i >> 4, c4 = i & 15;
        *(float4*)&sWl[r][c4 * 4] = ((const float4*)Wl)[i];
        *(float4*)&sWr[r][c4 * 4] = ((const float4*)Wr)[i];
    }
    int node0 = blockIdx.x * NPB;
    {
        int r = tid >> 4, c4 = tid & 15;
        int n = node0 + r;
        float4 xv = make_float4(0.f, 0.f, 0.f, 0.f), av = xv;
        if (n < nNodes) {
            xv = ((const float4*)(x + (size_t)n * 64))[c4];
            av = ((const float4*)(agg + (size_t)n * 64))[c4];
        }
        *(float4*)&sx[r][c4 * 4] = xv;
        *(float4*)&sa[r][c4 * 4] = av;
    }
    __syncthreads();

    int n  = tid & (NPB - 1);
    int o0 = (tid >> 4) * 8;
    float acc[8];
#pragma unroll
    for (int j = 0; j < 8; j++) acc[j] = bl[o0 + j];
    for (int k4 = 0; k4 < 16; k4++) {
        float4 xv = *(const float4*)&sx[n][k4 * 4];
        float4 av = *(const float4*)&sa[n][k4 * 4];
#pragma unroll
        for (int j = 0; j < 8; j++) {
            float4 wr = *(const float4*)&sWr[o0 + j][k4 * 4];
            float4 wl = *(const float4*)&sWl[o0 + j][k4 * 4];
            acc[j] += xv.x * wr.x + xv.y * wr.y + xv.z * wr.z + xv.w * wr.w
                    + av.x * wl.x + av.y * wl.y + av.z * wl.z + av.w * wl.w;
        }
    }
    int gn = node0 + n;
    if (gn < nNodes) {
#pragma unroll
        for (int j = 0; j < 8; j++)
            h[(size_t)gn * 128 + o0 + j] = tanhf(acc[j]);
    }
}

// ---------------------------------------------------------------------------
// K3: m2[n] = h[n] @ Wl2^T ; r2[n] = h[n] @ Wr2^T + b2
__global__ __launch_bounds__(256) void layer2a_kernel(
    const float* __restrict__ h, const float* __restrict__ Wl2,
    const float* __restrict__ bl2, const float* __restrict__ Wr2,
    float* __restrict__ m2, float* __restrict__ r2, int nNodes)
{
    __shared__ float sW[128][132];
    __shared__ float sh[16][132];
    int tid = threadIdx.x;

    for (int i = tid; i < 64 * 32; i += 256) {
        int r = i >> 5, c4 = i & 31;
        *(float4*)&sW[r][c4 * 4]      = ((const float4*)Wl2)[i];
        *(float4*)&sW[r + 64][c4 * 4] = ((const float4*)Wr2)[i];
    }
    int node0 = blockIdx.x * 16;
    for (int i = tid; i < 16 * 32; i += 256) {
        int r = i >> 5, c4 = i & 31;
        int n = node0 + r;
        float4 v = make_float4(0.f, 0.f, 0.f, 0.f);
        if (n < nNodes) v = ((const float4*)(h + (size_t)n * 128))[c4];
        *(float4*)&sh[r][c4 * 4] = v;
    }
    __syncthreads();

    int n  = tid & 15;
    int o0 = (tid >> 4) * 8;
    float acc[8];
#pragma unroll
    for (int j = 0; j < 8; j++)
        acc[j] = (o0 + j >= 64) ? bl2[o0 + j - 64] : 0.f;
    for (int k4 = 0; k4 < 32; k4++) {
        float4 hv = *(const float4*)&sh[n][k4 * 4];
#pragma unroll
        for (int j = 0; j < 8; j++) {
            float4 w = *(const float4*)&sW[o0 + j][k4 * 4];
            acc[j] += hv.x * w.x + hv.y * w.y + hv.z * w.z + hv.w * w.w;
        }
    }
    int gn = node0 + n;
    if (gn < nNodes) {
        if (o0 < 64) {
#pragma unroll
            for (int j = 0; j < 8; j++) m2[(size_t)gn * 64 + o0 + j] = acc[j];
        } else {
#pragma unroll
            for (int j = 0; j < 8; j++) r2[(size_t)gn * 64 + (o0 - 64) + j] = acc[j];
        }
    }
}

// ---------------------------------------------------------------------------
// Phase B fused: out[n] = log_softmax( mean(m2[src]) + r2[n] ).
// r2 already resides in `out`. One wave per node.
__global__ __launch_bounds__(256) void gather2_final_kernel(
    const float* __restrict__ m2, const int* __restrict__ perm,
    const int* __restrict__ off, float* __restrict__ out, int N)
{
    int wid  = (blockIdx.x * 256 + threadIdx.x) >> 6;
    int lane = threadIdx.x & 63;
    if (wid >= N) return;
    int lo = off[wid], hi = off[wid + 1];
    float s = gather_row_sum(m2, perm, lo, hi, lane);
    float inv = 1.f / fmaxf((float)(hi - lo), 1.f);
    float v = s * inv + out[(size_t)wid * 64 + lane];
    float m = v;
#pragma unroll
    for (int o = 32; o; o >>= 1) m = fmaxf(m, __shfl_xor(m, o, 64));
    float ex = expf(v - m);
    float sum = ex;
#pragma unroll
    for (int o = 32; o; o >>= 1) sum += __shfl_xor(sum, o, 64);
    out[(size_t)wid * 64 + lane] = (v - m) - logf(sum);
}

// ---------------------------------------------------------------------------
extern "C" void kernel_launch(void* const* d_in, const int* in_sizes, int n_in,
                              void* d_out, int out_size, void* d_ws, size_t ws_size,
                              hipStream_t stream)
{
    const float* x   = (const float*)d_in[0];
    const int*   ei  = (const int*)d_in[1];
    const float* Wl1 = (const float*)d_in[2];
    const float* bl1 = (const float*)d_in[3];
    const float* Wr1 = (const float*)d_in[4];
    const float* Wl2 = (const float*)d_in[5];
    const float* bl2 = (const float*)d_in[6];
    const float* Wr2 = (const float*)d_in[7];
    float* out = (float*)d_out;

    int N = in_sizes[0] / 64;   // 50000
    int E = in_sizes[1] / 2;    // 800000
    const int* src = ei;
    const int* dst = ei + E;

    // Workspace layout (ints then floats), all sizes rounded up to 64.
    char* wsb = (char*)d_ws;
    size_t npad = ((size_t)N + 64) & ~(size_t)63;   // room for N+1
    int* cnt  = (int*)wsb;                       // [N]
    int* off  = cnt + npad;                      // [N+1]
    int* cur  = off + npad;                      // [N]
    int* perm = cur + npad;                      // [E]
    size_t epad = ((size_t)E + 63) & ~(size_t)63;
    float* a64 = (float*)(perm + epad);          // [N*64]  agg1 then m2
    float* h   = a64 + (size_t)N * 64;           // [N*128]

    hipMemsetAsync(cnt, 0, (size_t)N * sizeof(int), stream);

    // CSR build (reused by both aggregation phases).
    count_kernel<<<(E + 255) / 256, 256, 0, stream>>>(dst, cnt, E);
    scan_kernel<<<1, 1024, 0, stream>>>(cnt, off, cur, N);
    fill_kernel<<<(E + 255) / 256, 256, 0, stream>>>(src, dst, cur, perm, E);

    // Phase 1: agg1 = mean of x over in-edges (pre-divided).
    gather1_kernel<<<(N * 64 + 255) / 256, 256, 0, stream>>>(x, perm, off, a64, N);

    // Phase 2: h = tanh(agg1 @ Wl1^T + b1 + x @ Wr1^T)
    layer1_kernel<<<(N + NPB - 1) / NPB, 256, 0, stream>>>(x, a64, Wl1, bl1, Wr1, h, N);

    // Phase 3: m2 = h @ Wl2^T (into a64), r2 = h @ Wr2^T + b2 (into out)
    layer2a_kernel<<<(N + 15) / 16, 256, 0, stream>>>(h, Wl2, bl2, Wr2, a64, out, N);

    // Phase 4+5 fused: out = log_softmax(mean of m2 over in-edges + r2)
    gather2_final_kernel<<<(N * 64 + 255) / 256, 256, 0, stream>>>(a64, perm, off, out, N);
}

// Round 3
// 338.109 us; speedup vs baseline: 1.7457x; 1.2801x over previous
//
#include <hip/hip_runtime.h>
#include <hip/hip_bf16.h>
#include <math.h>

// N=50000, E=800000, D_IN=64, D_HID=128, D_OUT=64
// Pipeline: CSR build (count / 3-stage scan / fill) -> gather1 -> layer1 ->
//           layer2 -> fused gather2+log_softmax.

// ---------------------------------------------------------------------------
// CSR build step 1: histogram of dst.
__global__ __launch_bounds__(256) void count_kernel(
    const int* __restrict__ dst, int* __restrict__ cnt, int E)
{
    int e = blockIdx.x * 256 + threadIdx.x;
    if (e < E) atomicAdd(&cnt[dst[e]], 1);
}

// ---------------------------------------------------------------------------
// 3-stage device-wide exclusive scan of cnt[0..N) -> off[0..N], cur copy.
// Chunk = 1024 elements per block (256 threads x 4).

__device__ __forceinline__ int wave_incl_scan(int v, int lane)
{
#pragma unroll
    for (int d = 1; d < 64; d <<= 1) {
        int u = __shfl_up(v, d, 64);
        if (lane >= d) v += u;
    }
    return v;
}

// Stage A: per-block chunk sums.
__global__ __launch_bounds__(256) void scan_a_kernel(
    const int* __restrict__ cnt, int* __restrict__ bsum, int N)
{
    __shared__ int wsum[4];
    int t = threadIdx.x, lane = t & 63, wv = t >> 6;
    int g0 = blockIdx.x * 1024 + t * 4;
    int s = 0;
#pragma unroll
    for (int j = 0; j < 4; j++) s += (g0 + j < N) ? cnt[g0 + j] : 0;
#pragma unroll
    for (int d = 32; d; d >>= 1) s += __shfl_xor(s, d, 64);
    if (lane == 0) wsum[wv] = s;
    __syncthreads();
    if (t == 0) bsum[blockIdx.x] = wsum[0] + wsum[1] + wsum[2] + wsum[3];
}

// Stage B: single block scans B<=1024 block sums -> exclusive bOff; off[N]=total.
__global__ __launch_bounds__(256) void scan_b_kernel(
    const int* __restrict__ bsum, int* __restrict__ bOff,
    int* __restrict__ off, int B, int N)
{
    __shared__ int wsum[4];
    int t = threadIdx.x, lane = t & 63, wv = t >> 6;
    int v[4];
    int s = 0;
#pragma unroll
    for (int j = 0; j < 4; j++) {
        int i = t * 4 + j;
        v[j] = (i < B) ? bsum[i] : 0;
        s += v[j];
    }
    int incl = wave_incl_scan(s, lane);
    if (lane == 63) wsum[wv] = incl;
    __syncthreads();
    int woff = 0;
    for (int i = 0; i < wv; i++) woff += wsum[i];
    int run = incl - s + woff;
#pragma unroll
    for (int j = 0; j < 4; j++) {
        int i = t * 4 + j;
        if (i < B) bOff[i] = run;
        run += v[j];
    }
    if (t == 255) off[N] = run;   // total = E
}

// Stage C: per-block exclusive scan + block offset -> off, cur.
__global__ __launch_bounds__(256) void scan_c_kernel(
    const int* __restrict__ cnt, const int* __restrict__ bOff,
    int* __restrict__ off, int* __restrict__ cur, int N)
{
    __shared__ int wsum[4];
    int t = threadIdx.x, lane = t & 63, wv = t >> 6;
    int g0 = blockIdx.x * 1024 + t * 4;
    int v[4];
    int s = 0;
#pragma unroll
    for (int j = 0; j < 4; j++) {
        v[j] = (g0 + j < N) ? cnt[g0 + j] : 0;
        s += v[j];
    }
    int incl = wave_incl_scan(s, lane);
    if (lane == 63) wsum[wv] = incl;
    __syncthreads();
    int woff = 0;
    for (int i = 0; i < wv; i++) woff += wsum[i];
    int run = incl - s + woff + bOff[blockIdx.x];
#pragma unroll
    for (int j = 0; j < 4; j++) {
        if (g0 + j < N) { off[g0 + j] = run; cur[g0 + j] = run; }
        run += v[j];
    }
}

// CSR build step 3: bucket src indices by dst via atomic ticket.
__global__ __launch_bounds__(256) void fill_kernel(
    const int* __restrict__ src, const int* __restrict__ dst,
    int* __restrict__ cur, int* __restrict__ perm, int E)
{
    int e = blockIdx.x * 256 + threadIdx.x;
    if (e >= E) return;
    int pos = atomicAdd(&cur[dst[e]], 1);
    perm[pos] = src[e];
}

// ---------------------------------------------------------------------------
// Wave-cooperative row gather-sum: lane = channel (64), rows = feat[idx*64..].
__device__ __forceinline__ float gather_row_sum(
    const float* __restrict__ feat, const int* __restrict__ perm,
    int lo, int hi, int lane)
{
    float a0 = 0.f, a1 = 0.f, a2 = 0.f, a3 = 0.f;
    for (int base = lo; base < hi; base += 64) {
        int cnt = min(64, hi - base);
        int pidx = (lane < cnt) ? perm[base + lane] : 0;
        int j = 0;
        for (; j + 4 <= cnt; j += 4) {
            int i0 = __shfl(pidx, j,     64);
            int i1 = __shfl(pidx, j + 1, 64);
            int i2 = __shfl(pidx, j + 2, 64);
            int i3 = __shfl(pidx, j + 3, 64);
            a0 += feat[(size_t)i0 * 64 + lane];
            a1 += feat[(size_t)i1 * 64 + lane];
            a2 += feat[(size_t)i2 * 64 + lane];
            a3 += feat[(size_t)i3 * 64 + lane];
        }
        for (; j < cnt; j++) {
            int i0 = __shfl(pidx, j, 64);
            a0 += feat[(size_t)i0 * 64 + lane];
        }
    }
    return (a0 + a1) + (a2 + a3);
}

// Phase A: agg1[n] = mean of x[src] over n's in-edges (pre-divided).
__global__ __launch_bounds__(256) void gather1_kernel(
    const float* __restrict__ x, const int* __restrict__ perm,
    const int* __restrict__ off, float* __restrict__ agg, int N)
{
    int wid  = (blockIdx.x * 256 + threadIdx.x) >> 6;
    int lane = threadIdx.x & 63;
    if (wid >= N) return;
    int lo = off[wid], hi = off[wid + 1];
    float s = gather_row_sum(x, perm, lo, hi, lane);
    float inv = 1.f / fmaxf((float)(hi - lo), 1.f);
    agg[(size_t)wid * 64 + lane] = s * inv;
}

// ---------------------------------------------------------------------------
// K2: h[n] = tanh( agg[n] @ Wl1^T + b1 + x[n] @ Wr1^T ); agg pre-divided.
#define NPB 16
__global__ __launch_bounds__(256) void layer1_kernel(
    const float* __restrict__ x, const float* __restrict__ agg,
    const float* __restrict__ Wl, const float* __restrict__ bl,
    const float* __restrict__ Wr, float* __restrict__ h, int nNodes)
{
    __shared__ float sWl[128][68];
    __shared__ float sWr[128][68];
    __shared__ float sx[NPB][68];
    __shared__ float sa[NPB][68];
    int tid = threadIdx.x;

    for (int i = tid; i < 128 * 16; i += 256) {
        int r = i >> 4, c4 = i & 15;
        *(float4*)&sWl[r][c4 * 4] = ((const float4*)Wl)[i];
        *(float4*)&sWr[r][c4 * 4] = ((const float4*)Wr)[i];
    }
    int node0 = blockIdx.x * NPB;
    {
        int r = tid >> 4, c4 = tid & 15;
        int n = node0 + r;
        float4 xv = make_float4(0.f, 0.f, 0.f, 0.f), av = xv;
        if (n < nNodes) {
            xv = ((const float4*)(x + (size_t)n * 64))[c4];
            av = ((const float4*)(agg + (size_t)n * 64))[c4];
        }
        *(float4*)&sx[r][c4 * 4] = xv;
        *(float4*)&sa[r][c4 * 4] = av;
    }
    __syncthreads();

    int n  = tid & (NPB - 1);
    int o0 = (tid >> 4) * 8;
    float acc[8];
#pragma unroll
    for (int j = 0; j < 8; j++) acc[j] = bl[o0 + j];
    for (int k4 = 0; k4 < 16; k4++) {
        float4 xv = *(const float4*)&sx[n][k4 * 4];
        float4 av = *(const float4*)&sa[n][k4 * 4];
#pragma unroll
        for (int j = 0; j < 8; j++) {
            float4 wr = *(const float4*)&sWr[o0 + j][k4 * 4];
            float4 wl = *(const float4*)&sWl[o0 + j][k4 * 4];
            acc[j] += xv.x * wr.x + xv.y * wr.y + xv.z * wr.z + xv.w * wr.w
                    + av.x * wl.x + av.y * wl.y + av.z * wl.z + av.w * wl.w;
        }
    }
    int gn = node0 + n;
    if (gn < nNodes) {
#pragma unroll
        for (int j = 0; j < 8; j++)
            h[(size_t)gn * 128 + o0 + j] = tanhf(acc[j]);
    }
}

// ---------------------------------------------------------------------------
// K3: m2[n] = h[n] @ Wl2^T ; r2[n] = h[n] @ Wr2^T + b2
__global__ __launch_bounds__(256) void layer2a_kernel(
    const float* __restrict__ h, const float* __restrict__ Wl2,
    const float* __restrict__ bl2, const float* __restrict__ Wr2,
    float* __restrict__ m2, float* __restrict__ r2, int nNodes)
{
    __shared__ float sW[128][132];
    __shared__ float sh[16][132];
    int tid = threadIdx.x;

    for (int i = tid; i < 64 * 32; i += 256) {
        int r = i >> 5, c4 = i & 31;
        *(float4*)&sW[r][c4 * 4]      = ((const float4*)Wl2)[i];
        *(float4*)&sW[r + 64][c4 * 4] = ((const float4*)Wr2)[i];
    }
    int node0 = blockIdx.x * 16;
    for (int i = tid; i < 16 * 32; i += 256) {
        int r = i >> 5, c4 = i & 31;
        int n = node0 + r;
        float4 v = make_float4(0.f, 0.f, 0.f, 0.f);
        if (n < nNodes) v = ((const float4*)(h + (size_t)n * 128))[c4];
        *(float4*)&sh[r][c4 * 4] = v;
    }
    __syncthreads();

    int n  = tid & 15;
    int o0 = (tid >> 4) * 8;
    float acc[8];
#pragma unroll
    for (int j = 0; j < 8; j++)
        acc[j] = (o0 + j >= 64) ? bl2[o0 + j - 64] : 0.f;
    for (int k4 = 0; k4 < 32; k4++) {
        float4 hv = *(const float4*)&sh[n][k4 * 4];
#pragma unroll
        for (int j = 0; j < 8; j++) {
            float4 w = *(const float4*)&sW[o0 + j][k4 * 4];
            acc[j] += hv.x * w.x + hv.y * w.y + hv.z * w.z + hv.w * w.w;
        }
    }
    int gn = node0 + n;
    if (gn < nNodes) {
        if (o0 < 64) {
#pragma unroll
            for (int j = 0; j < 8; j++) m2[(size_t)gn * 64 + o0 + j] = acc[j];
        } else {
#pragma unroll
            for (int j = 0; j < 8; j++) r2[(size_t)gn * 64 + (o0 - 64) + j] = acc[j];
        }
    }
}

// ---------------------------------------------------------------------------
// Phase B fused: out[n] = log_softmax( mean(m2[src]) + r2[n] ).
// r2 already resides in `out`. One wave per node.
__global__ __launch_bounds__(256) void gather2_final_kernel(
    const float* __restrict__ m2, const int* __restrict__ perm,
    const int* __restrict__ off, float* __restrict__ out, int N)
{
    int wid  = (blockIdx.x * 256 + threadIdx.x) >> 6;
    int lane = threadIdx.x & 63;
    if (wid >= N) return;
    int lo = off[wid], hi = off[wid + 1];
    float s = gather_row_sum(m2, perm, lo, hi, lane);
    float inv = 1.f / fmaxf((float)(hi - lo), 1.f);
    float v = s * inv + out[(size_t)wid * 64 + lane];
    float m = v;
#pragma unroll
    for (int o = 32; o; o >>= 1) m = fmaxf(m, __shfl_xor(m, o, 64));
    float ex = expf(v - m);
    float sum = ex;
#pragma unroll
    for (int o = 32; o; o >>= 1) sum += __shfl_xor(sum, o, 64);
    out[(size_t)wid * 64 + lane] = (v - m) - logf(sum);
}

// ---------------------------------------------------------------------------
extern "C" void kernel_launch(void* const* d_in, const int* in_sizes, int n_in,
                              void* d_out, int out_size, void* d_ws, size_t ws_size,
                              hipStream_t stream)
{
    const float* x   = (const float*)d_in[0];
    const int*   ei  = (const int*)d_in[1];
    const float* Wl1 = (const float*)d_in[2];
    const float* bl1 = (const float*)d_in[3];
    const float* Wr1 = (const float*)d_in[4];
    const float* Wl2 = (const float*)d_in[5];
    const float* bl2 = (const float*)d_in[6];
    const float* Wr2 = (const float*)d_in[7];
    float* out = (float*)d_out;

    int N = in_sizes[0] / 64;   // 50000
    int E = in_sizes[1] / 2;    // 800000
    const int* src = ei;
    const int* dst = ei + E;
    int B = (N + 1023) / 1024;  // scan chunks

    // Workspace layout.
    char* wsb = (char*)d_ws;
    size_t npad = ((size_t)N + 64) & ~(size_t)63;   // room for N+1
    int* cnt  = (int*)wsb;                       // [N]
    int* off  = cnt + npad;                      // [N+1]
    int* cur  = off + npad;                      // [N]
    int* bsum = cur + npad;                      // [B] (<=1024)
    int* bOff = bsum + 1024;                     // [B]
    int* perm = bOff + 1024;                     // [E]
    size_t epad = ((size_t)E + 63) & ~(size_t)63;
    float* a64 = (float*)(perm + epad);          // [N*64]  agg1 then m2
    float* h   = a64 + (size_t)N * 64;           // [N*128]

    hipMemsetAsync(cnt, 0, (size_t)N * sizeof(int), stream);

    // CSR build.
    count_kernel<<<(E + 255) / 256, 256, 0, stream>>>(dst, cnt, E);
    scan_a_kernel<<<B, 256, 0, stream>>>(cnt, bsum, N);
    scan_b_kernel<<<1, 256, 0, stream>>>(bsum, bOff, off, B, N);
    scan_c_kernel<<<B, 256, 0, stream>>>(cnt, bOff, off, cur, N);
    fill_kernel<<<(E + 255) / 256, 256, 0, stream>>>(src, dst, cur, perm, E);

    // Phase 1: agg1 = mean of x over in-edges (pre-divided).
    gather1_kernel<<<(N * 64 + 255) / 256, 256, 0, stream>>>(x, perm, off, a64, N);

    // Phase 2: h = tanh(agg1 @ Wl1^T + b1 + x @ Wr1^T)
    layer1_kernel<<<(N + NPB - 1) / NPB, 256, 0, stream>>>(x, a64, Wl1, bl1, Wr1, h, N);

    // Phase 3: m2 = h @ Wl2^T (into a64), r2 = h @ Wr2^T + b2 (into out)
    layer2a_kernel<<<(N + 15) / 16, 256, 0, stream>>>(h, Wl2, bl2, Wr2, a64, out, N);

    // Phase 4+5 fused: out = log_softmax(mean of m2 over in-edges + r2)
    gather2_final_kernel<<<(N * 64 + 255) / 256, 256, 0, stream>>>(a64, perm, off, out, N);
}

// Round 5
// 292.251 us; speedup vs baseline: 2.0196x; 1.1569x over previous
//
#include <hip/hip_runtime.h>
#include <hip/hip_bf16.h>
#include <math.h>

// N=50000, E=800000, D_IN=64, D_HID=128, D_OUT=64
// Pipeline: CSR build -> cvt(x->bf16) + weight pack(bf16) -> gather1(bf16) ->
//           layer1 (MFMA bf16) -> layer2 (MFMA bf16) -> gather2+log_softmax.

typedef unsigned short u16;
typedef unsigned int   u32;
typedef __attribute__((ext_vector_type(8))) __bf16 bf16x8;
typedef __attribute__((ext_vector_type(4))) float  f32x4;

__device__ __forceinline__ u16 f2bf(float f) {            // RNE fp32->bf16
    u32 u = __float_as_uint(f);
    u32 r = (u + 0x7FFFu + ((u >> 16) & 1u)) >> 16;
    return (u16)r;
}

// ---------------------------------------------------------------------------
// CSR build step 1: histogram of dst.
__global__ __launch_bounds__(256) void count_kernel(
    const int* __restrict__ dst, int* __restrict__ cnt, int E)
{
    int e = blockIdx.x * 256 + threadIdx.x;
    if (e < E) atomicAdd(&cnt[dst[e]], 1);
}

__device__ __forceinline__ int wave_incl_scan(int v, int lane)
{
#pragma unroll
    for (int d = 1; d < 64; d <<= 1) {
        int u = __shfl_up(v, d, 64);
        if (lane >= d) v += u;
    }
    return v;
}

// Stage A: per-block chunk sums (1024 elements/block).
__global__ __launch_bounds__(256) void scan_a_kernel(
    const int* __restrict__ cnt, int* __restrict__ bsum, int N)
{
    __shared__ int wsum[4];
    int t = threadIdx.x, lane = t & 63, wv = t >> 6;
    int g0 = blockIdx.x * 1024 + t * 4;
    int s = 0;
#pragma unroll
    for (int j = 0; j < 4; j++) s += (g0 + j < N) ? cnt[g0 + j] : 0;
#pragma unroll
    for (int d = 32; d; d >>= 1) s += __shfl_xor(s, d, 64);
    if (lane == 0) wsum[wv] = s;
    __syncthreads();
    if (t == 0) bsum[blockIdx.x] = wsum[0] + wsum[1] + wsum[2] + wsum[3];
}

// Stage B: single block scans B<=1024 block sums; off[N] = total.
__global__ __launch_bounds__(256) void scan_b_kernel(
    const int* __restrict__ bsum, int* __restrict__ bOff,
    int* __restrict__ off, int B, int N)
{
    __shared__ int wsum[4];
    int t = threadIdx.x, lane = t & 63, wv = t >> 6;
    int v[4];
    int s = 0;
#pragma unroll
    for (int j = 0; j < 4; j++) {
        int i = t * 4 + j;
        v[j] = (i < B) ? bsum[i] : 0;
        s += v[j];
    }
    int incl = wave_incl_scan(s, lane);
    if (lane == 63) wsum[wv] = incl;
    __syncthreads();
    int woff = 0;
    for (int i = 0; i < wv; i++) woff += wsum[i];
    int run = incl - s + woff;
#pragma unroll
    for (int j = 0; j < 4; j++) {
        int i = t * 4 + j;
        if (i < B) bOff[i] = run;
        run += v[j];
    }
    if (t == 255) off[N] = run;
}

// Stage C: per-block exclusive scan + block offset -> off, cur.
__global__ __launch_bounds__(256) void scan_c_kernel(
    const int* __restrict__ cnt, const int* __restrict__ bOff,
    int* __restrict__ off, int* __restrict__ cur, int N)
{
    __shared__ int wsum[4];
    int t = threadIdx.x, lane = t & 63, wv = t >> 6;
    int g0 = blockIdx.x * 1024 + t * 4;
    int v[4];
    int s = 0;
#pragma unroll
    for (int j = 0; j < 4; j++) {
        v[j] = (g0 + j < N) ? cnt[g0 + j] : 0;
        s += v[j];
    }
    int incl = wave_incl_scan(s, lane);
    if (lane == 63) wsum[wv] = incl;
    __syncthreads();
    int woff = 0;
    for (int i = 0; i < wv; i++) woff += wsum[i];
    int run = incl - s + woff + bOff[blockIdx.x];
#pragma unroll
    for (int j = 0; j < 4; j++) {
        if (g0 + j < N) { off[g0 + j] = run; cur[g0 + j] = run; }
        run += v[j];
    }
}

// CSR build step 3: bucket src indices by dst via atomic ticket.
__global__ __launch_bounds__(256) void fill_kernel(
    const int* __restrict__ src, const int* __restrict__ dst,
    int* __restrict__ cur, int* __restrict__ perm, int E)
{
    int e = blockIdx.x * 256 + threadIdx.x;
    if (e >= E) return;
    int pos = atomicAdd(&cur[dst[e]], 1);
    perm[pos] = src[e];
}

// ---------------------------------------------------------------------------
// cvt: x fp32 -> xb bf16, 4 elements/thread.
__global__ __launch_bounds__(256) void cvt_kernel(
    const float* __restrict__ x, u32* __restrict__ xb2, int total4)
{
    int i = blockIdx.x * 256 + threadIdx.x;
    if (i >= total4) return;
    float4 v = ((const float4*)x)[i];
    u32 lo = (u32)f2bf(v.x) | ((u32)f2bf(v.y) << 16);
    u32 hi = (u32)f2bf(v.z) | ((u32)f2bf(v.w) << 16);
    xb2[i * 2]     = lo;
    xb2[i * 2 + 1] = hi;
}

// Weight pack: W1c[o][k] = k<64 ? Wr1[o][k] : Wl1[o][k-64]   (128x128 bf16)
//              W2c[o][k] = o<64 ? Wl2[o][k] : Wr2[o-64][k]   (128x128 bf16)
__global__ __launch_bounds__(256) void prep_w_kernel(
    const float* __restrict__ Wl1, const float* __restrict__ Wr1,
    const float* __restrict__ Wl2, const float* __restrict__ Wr2,
    u16* __restrict__ W1c, u16* __restrict__ W2c)
{
    int i = blockIdx.x * 256 + threadIdx.x;
    if (i >= 128 * 128) return;
    int o = i >> 7, k = i & 127;
    float w1 = (k < 64) ? Wr1[o * 64 + k] : Wl1[o * 64 + (k - 64)];
    W1c[i] = f2bf(w1);
    float w2 = (o < 64) ? Wl2[o * 128 + k] : Wr2[(o - 64) * 128 + k];
    W2c[i] = f2bf(w2);
}

// ---------------------------------------------------------------------------
// gather1: aggb[n] = bf16( mean of xb[src] rows ). One wave per node.
__global__ __launch_bounds__(256) void gather1_kernel(
    const u32* __restrict__ xb2, const int* __restrict__ perm,
    const int* __restrict__ off, u32* __restrict__ aggb2, int N)
{
    int wid  = blockIdx.x * 4 + (threadIdx.x >> 6);
    int lane = threadIdx.x & 63;
    if (wid >= N) return;
    int lo = off[wid], hi = off[wid + 1];
    int half = lane >> 5, c = lane & 31;
    float s0 = 0.f, s1 = 0.f;
    for (int base = lo; base < hi; base += 64) {
        int rem = min(64, hi - base);
        int pidx = (lane < rem) ? perm[base + lane] : 0;
        for (int j = 0; j < rem; j += 2) {
            int r = j + half;
            int row = __shfl(pidx, r, 64);
            u32 u = 0;
            if (r < rem) u = xb2[(size_t)row * 32 + c];
            s0 += __uint_as_float(u << 16);
            s1 += __uint_as_float(u & 0xFFFF0000u);
        }
    }
    s0 += __shfl_xor(s0, 32, 64);
    s1 += __shfl_xor(s1, 32, 64);
    if (half == 0) {
        float inv = 1.f / fmaxf((float)(hi - lo), 1.f);
        aggb2[(size_t)wid * 32 + c] =
            (u32)f2bf(s0 * inv) | ((u32)f2bf(s1 * inv) << 16);
    }
}

// ---------------------------------------------------------------------------
// layer1: hb[n] = bf16( tanh( [xb|aggb] @ W1c^T + b1 ) ), MFMA 16x16x32 bf16.
// A frag: A[m=l16][k=quad*8+j]; B frag: B[k=quad*8+j][n=l16] = W[n][quad*8+j].
__global__ __launch_bounds__(256) void layer1_mfma(
    const u16* __restrict__ xb, const u16* __restrict__ aggb,
    const u16* __restrict__ W1, const float* __restrict__ b1,
    u16* __restrict__ hb, int N)
{
    int tid = threadIdx.x;
    int wv = tid >> 6, lane = tid & 63;
    int quad = lane >> 4, l16 = lane & 15;
    int node = blockIdx.x * 64 + wv * 16 + l16;
    int nclamp = min(node, N - 1);
    const u16* xrow = xb   + (size_t)nclamp * 64;
    const u16* arow = aggb + (size_t)nclamp * 64;
    bf16x8 a0 = *(const bf16x8*)(xrow + quad * 8);
    bf16x8 a1 = *(const bf16x8*)(xrow + 32 + quad * 8);
    bf16x8 a2 = *(const bf16x8*)(arow + quad * 8);
    bf16x8 a3 = *(const bf16x8*)(arow + 32 + quad * 8);
    int orow = blockIdx.x * 64 + wv * 16 + quad * 4;   // D rows = nodes
#pragma unroll
    for (int nt = 0; nt < 8; nt++) {
        const u16* wrow = W1 + (size_t)(nt * 16 + l16) * 128 + quad * 8;
        f32x4 acc = {0.f, 0.f, 0.f, 0.f};
        acc = __builtin_amdgcn_mfma_f32_16x16x32_bf16(a0, *(const bf16x8*)(wrow),      acc, 0, 0, 0);
        acc = __builtin_amdgcn_mfma_f32_16x16x32_bf16(a1, *(const bf16x8*)(wrow + 32), acc, 0, 0, 0);
        acc = __builtin_amdgcn_mfma_f32_16x16x32_bf16(a2, *(const bf16x8*)(wrow + 64), acc, 0, 0, 0);
        acc = __builtin_amdgcn_mfma_f32_16x16x32_bf16(a3, *(const bf16x8*)(wrow + 96), acc, 0, 0, 0);
        int oc = nt * 16 + l16;                         // D col = output chan
        float bias = b1[oc];
#pragma unroll
        for (int r = 0; r < 4; r++) {
            int nn = orow + r;
            if (nn < N) hb[(size_t)nn * 128 + oc] = f2bf(tanhf(acc[r] + bias));
        }
    }
}

// layer2: m2b[n] = bf16( hb @ Wl2^T ), r2 (into out) = hb @ Wr2^T + b2.
__global__ __launch_bounds__(256) void layer2_mfma(
    const u16* __restrict__ hb, const u16* __restrict__ W2,
    const float* __restrict__ b2, u16* __restrict__ m2b,
    float* __restrict__ out, int N)
{
    int tid = threadIdx.x;
    int wv = tid >> 6, lane = tid & 63;
    int quad = lane >> 4, l16 = lane & 15;
    int node = blockIdx.x * 64 + wv * 16 + l16;
    int nclamp = min(node, N - 1);
    const u16* hrow = hb + (size_t)nclamp * 128;
    bf16x8 a0 = *(const bf16x8*)(hrow + quad * 8);
    bf16x8 a1 = *(const bf16x8*)(hrow + 32 + quad * 8);
    bf16x8 a2 = *(const bf16x8*)(hrow + 64 + quad * 8);
    bf16x8 a3 = *(const bf16x8*)(hrow + 96 + quad * 8);
    int orow = blockIdx.x * 64 + wv * 16 + quad * 4;
#pragma unroll
    for (int nt = 0; nt < 8; nt++) {
        const u16* wrow = W2 + (size_t)(nt * 16 + l16) * 128 + quad * 8;
        f32x4 acc = {0.f, 0.f, 0.f, 0.f};
        acc = __builtin_amdgcn_mfma_f32_16x16x32_bf16(a0, *(const bf16x8*)(wrow),      acc, 0, 0, 0);
        acc = __builtin_amdgcn_mfma_f32_16x16x32_bf16(a1, *(const bf16x8*)(wrow + 32), acc, 0, 0, 0);
        acc = __builtin_amdgcn_mfma_f32_16x16x32_bf16(a2, *(const bf16x8*)(wrow + 64), acc, 0, 0, 0);
        acc = __builtin_amdgcn_mfma_f32_16x16x32_bf16(a3, *(const bf16x8*)(wrow + 96), acc, 0, 0, 0);
        int oc = nt * 16 + l16;
#pragma unroll
        for (int r = 0; r < 4; r++) {
            int nn = orow + r;
            if (nn >= N) continue;
            if (oc < 64) m2b[(size_t)nn * 64 + oc] = f2bf(acc[r]);
            else         out[(size_t)nn * 64 + (oc - 64)] = acc[r] + b2[oc - 64];
        }
    }
}

// ---------------------------------------------------------------------------
// gather2+final: out[n] = log_softmax( mean(m2b[src]) + r2[n] ). r2 is in out.
__global__ __launch_bounds__(256) void gather2_final_kernel(
    const u32* __restrict__ m2b2, const int* __restrict__ perm,
    const int* __restrict__ off, float* __restrict__ out, int N)
{
    int wid  = blockIdx.x * 4 + (threadIdx.x >> 6);
    int lane = threadIdx.x & 63;
    if (wid >= N) return;
    int lo = off[wid], hi = off[wid + 1];
    int half = lane >> 5, c = lane & 31;
    float s0 = 0.f, s1 = 0.f;
    for (int base = lo; base < hi; base += 64) {
        int rem = min(64, hi - base);
        int pidx = (lane < rem) ? perm[base + lane] : 0;
        for (int j = 0; j < rem; j += 2) {
            int r = j + half;
            int row = __shfl(pidx, r, 64);
            u32 u = 0;
            if (r < rem) u = m2b2[(size_t)row * 32 + c];
            s0 += __uint_as_float(u << 16);
            s1 += __uint_as_float(u & 0xFFFF0000u);
        }
    }
    s0 += __shfl_xor(s0, 32, 64);
    s1 += __shfl_xor(s1, 32, 64);
    float inv = 1.f / fmaxf((float)(hi - lo), 1.f);
    float2 r2 = *(const float2*)(out + (size_t)wid * 64 + c * 2);
    float v0 = s0 * inv + r2.x;
    float v1 = s1 * inv + r2.y;
    float m = fmaxf(v0, v1);
#pragma unroll
    for (int o = 16; o; o >>= 1) m = fmaxf(m, __shfl_xor(m, o, 64));
    float sum = expf(v0 - m) + expf(v1 - m);
#pragma unroll
    for (int o = 16; o; o >>= 1) sum += __shfl_xor(sum, o, 64);
    if (half == 0) {
        float ls = logf(sum);
        float2 res = make_float2(v0 - m - ls, v1 - m - ls);
        *(float2*)(out + (size_t)wid * 64 + c * 2) = res;
    }
}

// ---------------------------------------------------------------------------
extern "C" void kernel_launch(void* const* d_in, const int* in_sizes, int n_in,
                              void* d_out, int out_size, void* d_ws, size_t ws_size,
                              hipStream_t stream)
{
    const float* x   = (const float*)d_in[0];
    const int*   ei  = (const int*)d_in[1];
    const float* Wl1 = (const float*)d_in[2];
    const float* bl1 = (const float*)d_in[3];
    const float* Wr1 = (const float*)d_in[4];
    const float* Wl2 = (const float*)d_in[5];
    const float* bl2 = (const float*)d_in[6];
    const float* Wr2 = (const float*)d_in[7];
    float* out = (float*)d_out;

    int N = in_sizes[0] / 64;   // 50000
    int E = in_sizes[1] / 2;    // 800000
    const int* src = ei;
    const int* dst = ei + E;
    int B = (N + 1023) / 1024;

    // Workspace layout.
    char* wsb = (char*)d_ws;
    size_t npad = ((size_t)N + 64) & ~(size_t)63;
    int* cnt  = (int*)wsb;                       // [N]
    int* off  = cnt + npad;                      // [N+1]
    int* cur  = off + npad;                      // [N]
    int* bsum = cur + npad;                      // [<=1024]
    int* bOff = bsum + 1024;
    int* perm = bOff + 1024;                     // [E]
    size_t epad = ((size_t)E + 63) & ~(size_t)63;
    u16* xb   = (u16*)(perm + epad);             // [N*64]  bf16
    u16* aggb = xb + (size_t)N * 64;             // [N*64]  bf16
    u16* hb   = aggb + (size_t)N * 64;           // [N*128] bf16
    u16* m2b  = hb + (size_t)N * 128;            // [N*64]  bf16
    u16* W1c  = m2b + (size_t)N * 64;            // [128*128]
    u16* W2c  = W1c + 128 * 128;                 // [128*128]

    hipMemsetAsync(cnt, 0, (size_t)N * sizeof(int), stream);

    // CSR build.
    count_kernel<<<(E + 255) / 256, 256, 0, stream>>>(dst, cnt, E);
    scan_a_kernel<<<B, 256, 0, stream>>>(cnt, bsum, N);
    scan_b_kernel<<<1, 256, 0, stream>>>(bsum, bOff, off, B, N);
    scan_c_kernel<<<B, 256, 0, stream>>>(cnt, bOff, off, cur, N);
    fill_kernel<<<(E + 255) / 256, 256, 0, stream>>>(src, dst, cur, perm, E);

    // bf16 conversions.
    int total4 = N * 64 / 4;
    cvt_kernel<<<(total4 + 255) / 256, 256, 0, stream>>>(x, (u32*)xb, total4);
    prep_w_kernel<<<64, 256, 0, stream>>>(Wl1, Wr1, Wl2, Wr2, W1c, W2c);

    // Phase 1: aggb = bf16(mean of xb over in-edges).
    gather1_kernel<<<(N + 3) / 4, 256, 0, stream>>>((const u32*)xb, perm, off,
                                                    (u32*)aggb, N);
    // Phase 2: hb = bf16(tanh([xb|aggb] @ W1c^T + b1))
    layer1_mfma<<<(N + 63) / 64, 256, 0, stream>>>(xb, aggb, W1c, bl1, hb, N);

    // Phase 3: m2b = bf16(hb @ Wl2^T); r2 = hb @ Wr2^T + b2 -> out
    layer2_mfma<<<(N + 63) / 64, 256, 0, stream>>>(hb, W2c, bl2, m2b, out, N);

    // Phase 4+5: out = log_softmax(mean(m2b) + r2)
    gather2_final_kernel<<<(N + 3) / 4, 256, 0, stream>>>((const u32*)m2b, perm,
                                                          off, out, N);
}

// Round 6
// 275.175 us; speedup vs baseline: 2.1449x; 1.0621x over previous
//
#include <hip/hip_runtime.h>
#include <hip/hip_bf16.h>
#include <math.h>

// N=50000, E=800000, D_IN=64, D_HID=128, D_OUT=64
// Pipeline: CSR build (count / scan / bucketed fill, perm=u16) -> cvt/prep ->
//           gather1(bf16) -> layer1(MFMA) -> layer2(MFMA) -> gather2+logsoftmax.

typedef unsigned short u16;
typedef unsigned int   u32;
typedef __attribute__((ext_vector_type(8))) __bf16 bf16x8;
typedef __attribute__((ext_vector_type(4))) float  f32x4;

__device__ __forceinline__ u16 f2bf(float f) {            // RNE fp32->bf16
    u32 u = __float_as_uint(f);
    u32 r = (u + 0x7FFFu + ((u >> 16) & 1u)) >> 16;
    return (u16)r;
}

// ---------------------------------------------------------------------------
// CSR build step 1: histogram of dst.
__global__ __launch_bounds__(256) void count_kernel(
    const int* __restrict__ dst, int* __restrict__ cnt, int E)
{
    int e = blockIdx.x * 256 + threadIdx.x;
    if (e < E) atomicAdd(&cnt[dst[e]], 1);
}

__device__ __forceinline__ int wave_incl_scan(int v, int lane)
{
#pragma unroll
    for (int d = 1; d < 64; d <<= 1) {
        int u = __shfl_up(v, d, 64);
        if (lane >= d) v += u;
    }
    return v;
}

// Stage A: per-block chunk sums (1024 elements/block).
__global__ __launch_bounds__(256) void scan_a_kernel(
    const int* __restrict__ cnt, int* __restrict__ bsum, int N)
{
    __shared__ int wsum[4];
    int t = threadIdx.x, lane = t & 63, wv = t >> 6;
    int g0 = blockIdx.x * 1024 + t * 4;
    int s = 0;
#pragma unroll
    for (int j = 0; j < 4; j++) s += (g0 + j < N) ? cnt[g0 + j] : 0;
#pragma unroll
    for (int d = 32; d; d >>= 1) s += __shfl_xor(s, d, 64);
    if (lane == 0) wsum[wv] = s;
    __syncthreads();
    if (t == 0) bsum[blockIdx.x] = wsum[0] + wsum[1] + wsum[2] + wsum[3];
}

// Stage B: single block scans B<=1024 block sums; off[N] = total.
__global__ __launch_bounds__(256) void scan_b_kernel(
    const int* __restrict__ bsum, int* __restrict__ bOff,
    int* __restrict__ off, int B, int N)
{
    __shared__ int wsum[4];
    int t = threadIdx.x, lane = t & 63, wv = t >> 6;
    int v[4];
    int s = 0;
#pragma unroll
    for (int j = 0; j < 4; j++) {
        int i = t * 4 + j;
        v[j] = (i < B) ? bsum[i] : 0;
        s += v[j];
    }
    int incl = wave_incl_scan(s, lane);
    if (lane == 63) wsum[wv] = incl;
    __syncthreads();
    int woff = 0;
    for (int i = 0; i < wv; i++) woff += wsum[i];
    int run = incl - s + woff;
#pragma unroll
    for (int j = 0; j < 4; j++) {
        int i = t * 4 + j;
        if (i < B) bOff[i] = run;
        run += v[j];
    }
    if (t == 255) off[N] = run;
}

// Stage C: per-block exclusive scan + block offset -> off, cur.
__global__ __launch_bounds__(256) void scan_c_kernel(
    const int* __restrict__ cnt, const int* __restrict__ bOff,
    int* __restrict__ off, int* __restrict__ cur, int N)
{
    __shared__ int wsum[4];
    int t = threadIdx.x, lane = t & 63, wv = t >> 6;
    int g0 = blockIdx.x * 1024 + t * 4;
    int v[4];
    int s = 0;
#pragma unroll
    for (int j = 0; j < 4; j++) {
        v[j] = (g0 + j < N) ? cnt[g0 + j] : 0;
        s += v[j];
    }
    int incl = wave_incl_scan(s, lane);
    if (lane == 63) wsum[wv] = incl;
    __syncthreads();
    int woff = 0;
    for (int i = 0; i < wv; i++) woff += wsum[i];
    int run = incl - s + woff + bOff[blockIdx.x];
#pragma unroll
    for (int j = 0; j < 4; j++) {
        if (g0 + j < N) { off[g0 + j] = run; cur[g0 + j] = run; }
        run += v[j];
    }
}

// CSR build step 3: bucketed fill. Nodes split into 8 contiguous buckets of
// N8; block (chunk, g=blockIdx&7) scans its chunk, commits only dst-bucket g.
// All bucket-g writers land on one XCD (blockIdx%8 heuristic) -> perm writes
// stay in that XCD's L2 and evict as full lines. perm is u16 (src < 65536).
#define FILL_EPT 8   // edges per thread -> 2048 per block
__global__ __launch_bounds__(256) void fill_kernel(
    const int* __restrict__ src, const int* __restrict__ dst,
    int* __restrict__ cur, u16* __restrict__ perm, int E, int N8, float invN8)
{
    int g = blockIdx.x & 7;
    int base = (blockIdx.x >> 3) * (256 * FILL_EPT) + threadIdx.x;
#pragma unroll
    for (int i = 0; i < FILL_EPT; i++) {
        int e = base + i * 256;
        if (e >= E) continue;
        int d = dst[e];
        int b = (int)((float)d * invN8);
        if (d >= (b + 1) * N8) b++;
        else if (d < b * N8) b--;
        if (b != g) continue;
        int pos = atomicAdd(&cur[d], 1);
        perm[pos] = (u16)src[e];
    }
}

// ---------------------------------------------------------------------------
// cvt: x fp32 -> xb bf16, 4 elements/thread.
__global__ __launch_bounds__(256) void cvt_kernel(
    const float* __restrict__ x, u32* __restrict__ xb2, int total4)
{
    int i = blockIdx.x * 256 + threadIdx.x;
    if (i >= total4) return;
    float4 v = ((const float4*)x)[i];
    u32 lo = (u32)f2bf(v.x) | ((u32)f2bf(v.y) << 16);
    u32 hi = (u32)f2bf(v.z) | ((u32)f2bf(v.w) << 16);
    xb2[i * 2]     = lo;
    xb2[i * 2 + 1] = hi;
}

// Weight pack: W1c[o][k] = k<64 ? Wr1[o][k] : Wl1[o][k-64]   (128x128 bf16)
//              W2c[o][k] = o<64 ? Wl2[o][k] : Wr2[o-64][k]   (128x128 bf16)
__global__ __launch_bounds__(256) void prep_w_kernel(
    const float* __restrict__ Wl1, const float* __restrict__ Wr1,
    const float* __restrict__ Wl2, const float* __restrict__ Wr2,
    u16* __restrict__ W1c, u16* __restrict__ W2c)
{
    int i = blockIdx.x * 256 + threadIdx.x;
    if (i >= 128 * 128) return;
    int o = i >> 7, k = i & 127;
    float w1 = (k < 64) ? Wr1[o * 64 + k] : Wl1[o * 64 + (k - 64)];
    W1c[i] = f2bf(w1);
    float w2 = (o < 64) ? Wl2[o * 128 + k] : Wr2[(o - 64) * 128 + k];
    W2c[i] = f2bf(w2);
}

// ---------------------------------------------------------------------------
// gather1: aggb[n] = bf16( mean of xb[src] rows ). One wave per node.
__global__ __launch_bounds__(256) void gather1_kernel(
    const u32* __restrict__ xb2, const u16* __restrict__ perm,
    const int* __restrict__ off, u32* __restrict__ aggb2, int N)
{
    int wid  = blockIdx.x * 4 + (threadIdx.x >> 6);
    int lane = threadIdx.x & 63;
    if (wid >= N) return;
    int lo = off[wid], hi = off[wid + 1];
    int half = lane >> 5, c = lane & 31;
    float s0 = 0.f, s1 = 0.f;
    for (int base = lo; base < hi; base += 64) {
        int rem = min(64, hi - base);
        int pidx = (lane < rem) ? (int)perm[base + lane] : 0;
        for (int j = 0; j < rem; j += 2) {
            int r = j + half;
            int row = __shfl(pidx, r, 64);
            u32 u = 0;
            if (r < rem) u = xb2[(size_t)row * 32 + c];
            s0 += __uint_as_float(u << 16);
            s1 += __uint_as_float(u & 0xFFFF0000u);
        }
    }
    s0 += __shfl_xor(s0, 32, 64);
    s1 += __shfl_xor(s1, 32, 64);
    if (half == 0) {
        float inv = 1.f / fmaxf((float)(hi - lo), 1.f);
        aggb2[(size_t)wid * 32 + c] =
            (u32)f2bf(s0 * inv) | ((u32)f2bf(s1 * inv) << 16);
    }
}

// ---------------------------------------------------------------------------
// layer1: hb[n] = bf16( tanh( [xb|aggb] @ W1c^T + b1 ) ), MFMA 16x16x32 bf16.
// A frag: A[m=l16][k=quad*8+j]; B frag: B[k=quad*8+j][n=l16] = W[n][quad*8+j].
__global__ __launch_bounds__(256) void layer1_mfma(
    const u16* __restrict__ xb, const u16* __restrict__ aggb,
    const u16* __restrict__ W1, const float* __restrict__ b1,
    u16* __restrict__ hb, int N)
{
    int tid = threadIdx.x;
    int wv = tid >> 6, lane = tid & 63;
    int quad = lane >> 4, l16 = lane & 15;
    int node = blockIdx.x * 64 + wv * 16 + l16;
    int nclamp = min(node, N - 1);
    const u16* xrow = xb   + (size_t)nclamp * 64;
    const u16* arow = aggb + (size_t)nclamp * 64;
    bf16x8 a0 = *(const bf16x8*)(xrow + quad * 8);
    bf16x8 a1 = *(const bf16x8*)(xrow + 32 + quad * 8);
    bf16x8 a2 = *(const bf16x8*)(arow + quad * 8);
    bf16x8 a3 = *(const bf16x8*)(arow + 32 + quad * 8);
    int orow = blockIdx.x * 64 + wv * 16 + quad * 4;   // D rows = nodes
#pragma unroll
    for (int nt = 0; nt < 8; nt++) {
        const u16* wrow = W1 + (size_t)(nt * 16 + l16) * 128 + quad * 8;
        f32x4 acc = {0.f, 0.f, 0.f, 0.f};
        acc = __builtin_amdgcn_mfma_f32_16x16x32_bf16(a0, *(const bf16x8*)(wrow),      acc, 0, 0, 0);
        acc = __builtin_amdgcn_mfma_f32_16x16x32_bf16(a1, *(const bf16x8*)(wrow + 32), acc, 0, 0, 0);
        acc = __builtin_amdgcn_mfma_f32_16x16x32_bf16(a2, *(const bf16x8*)(wrow + 64), acc, 0, 0, 0);
        acc = __builtin_amdgcn_mfma_f32_16x16x32_bf16(a3, *(const bf16x8*)(wrow + 96), acc, 0, 0, 0);
        int oc = nt * 16 + l16;                         // D col = output chan
        float bias = b1[oc];
#pragma unroll
        for (int r = 0; r < 4; r++) {
            int nn = orow + r;
            if (nn < N) hb[(size_t)nn * 128 + oc] = f2bf(tanhf(acc[r] + bias));
        }
    }
}

// layer2: m2b[n] = bf16( hb @ Wl2^T ), r2 (into out) = hb @ Wr2^T + b2.
__global__ __launch_bounds__(256) void layer2_mfma(
    const u16* __restrict__ hb, const u16* __restrict__ W2,
    const float* __restrict__ b2, u16* __restrict__ m2b,
    float* __restrict__ out, int N)
{
    int tid = threadIdx.x;
    int wv = tid >> 6, lane = tid & 63;
    int quad = lane >> 4, l16 = lane & 15;
    int node = blockIdx.x * 64 + wv * 16 + l16;
    int nclamp = min(node, N - 1);
    const u16* hrow = hb + (size_t)nclamp * 128;
    bf16x8 a0 = *(const bf16x8*)(hrow + quad * 8);
    bf16x8 a1 = *(const bf16x8*)(hrow + 32 + quad * 8);
    bf16x8 a2 = *(const bf16x8*)(hrow + 64 + quad * 8);
    bf16x8 a3 = *(const bf16x8*)(hrow + 96 + quad * 8);
    int orow = blockIdx.x * 64 + wv * 16 + quad * 4;
#pragma unroll
    for (int nt = 0; nt < 8; nt++) {
        const u16* wrow = W2 + (size_t)(nt * 16 + l16) * 128 + quad * 8;
        f32x4 acc = {0.f, 0.f, 0.f, 0.f};
        acc = __builtin_amdgcn_mfma_f32_16x16x32_bf16(a0, *(const bf16x8*)(wrow),      acc, 0, 0, 0);
        acc = __builtin_amdgcn_mfma_f32_16x16x32_bf16(a1, *(const bf16x8*)(wrow + 32), acc, 0, 0, 0);
        acc = __builtin_amdgcn_mfma_f32_16x16x32_bf16(a2, *(const bf16x8*)(wrow + 64), acc, 0, 0, 0);
        acc = __builtin_amdgcn_mfma_f32_16x16x32_bf16(a3, *(const bf16x8*)(wrow + 96), acc, 0, 0, 0);
        int oc = nt * 16 + l16;
#pragma unroll
        for (int r = 0; r < 4; r++) {
            int nn = orow + r;
            if (nn >= N) continue;
            if (oc < 64) m2b[(size_t)nn * 64 + oc] = f2bf(acc[r]);
            else         out[(size_t)nn * 64 + (oc - 64)] = acc[r] + b2[oc - 64];
        }
    }
}

// ---------------------------------------------------------------------------
// gather2+final: out[n] = log_softmax( mean(m2b[src]) + r2[n] ). r2 is in out.
__global__ __launch_bounds__(256) void gather2_final_kernel(
    const u32* __restrict__ m2b2, const u16* __restrict__ perm,
    const int* __restrict__ off, float* __restrict__ out, int N)
{
    int wid  = blockIdx.x * 4 + (threadIdx.x >> 6);
    int lane = threadIdx.x & 63;
    if (wid >= N) return;
    int lo = off[wid], hi = off[wid + 1];
    int half = lane >> 5, c = lane & 31;
    float s0 = 0.f, s1 = 0.f;
    for (int base = lo; base < hi; base += 64) {
        int rem = min(64, hi - base);
        int pidx = (lane < rem) ? (int)perm[base + lane] : 0;
        for (int j = 0; j < rem; j += 2) {
            int r = j + half;
            int row = __shfl(pidx, r, 64);
            u32 u = 0;
            if (r < rem) u = m2b2[(size_t)row * 32 + c];
            s0 += __uint_as_float(u << 16);
            s1 += __uint_as_float(u & 0xFFFF0000u);
        }
    }
    s0 += __shfl_xor(s0, 32, 64);
    s1 += __shfl_xor(s1, 32, 64);
    float inv = 1.f / fmaxf((float)(hi - lo), 1.f);
    float2 r2 = *(const float2*)(out + (size_t)wid * 64 + c * 2);
    float v0 = s0 * inv + r2.x;
    float v1 = s1 * inv + r2.y;
    float m = fmaxf(v0, v1);
#pragma unroll
    for (int o = 16; o; o >>= 1) m = fmaxf(m, __shfl_xor(m, o, 64));
    float sum = expf(v0 - m) + expf(v1 - m);
#pragma unroll
    for (int o = 16; o; o >>= 1) sum += __shfl_xor(sum, o, 64);
    if (half == 0) {
        float ls = logf(sum);
        float2 res = make_float2(v0 - m - ls, v1 - m - ls);
        *(float2*)(out + (size_t)wid * 64 + c * 2) = res;
    }
}

// ---------------------------------------------------------------------------
extern "C" void kernel_launch(void* const* d_in, const int* in_sizes, int n_in,
                              void* d_out, int out_size, void* d_ws, size_t ws_size,
                              hipStream_t stream)
{
    const float* x   = (const float*)d_in[0];
    const int*   ei  = (const int*)d_in[1];
    const float* Wl1 = (const float*)d_in[2];
    const float* bl1 = (const float*)d_in[3];
    const float* Wr1 = (const float*)d_in[4];
    const float* Wl2 = (const float*)d_in[5];
    const float* bl2 = (const float*)d_in[6];
    const float* Wr2 = (const float*)d_in[7];
    float* out = (float*)d_out;

    int N = in_sizes[0] / 64;   // 50000
    int E = in_sizes[1] / 2;    // 800000
    const int* src = ei;
    const int* dst = ei + E;
    int B = (N + 1023) / 1024;
    int N8 = (N + 7) / 8;
    float invN8 = 1.0f / (float)N8;

    // Workspace layout.
    char* wsb = (char*)d_ws;
    size_t npad = ((size_t)N + 64) & ~(size_t)63;
    int* cnt  = (int*)wsb;                       // [N]
    int* off  = cnt + npad;                      // [N+1]
    int* cur  = off + npad;                      // [N]
    int* bsum = cur + npad;                      // [<=1024]
    int* bOff = bsum + 1024;
    u16* perm = (u16*)(bOff + 1024);             // [E] u16
    size_t epad = ((size_t)E + 63) & ~(size_t)63;
    u16* xb   = perm + epad;                     // [N*64]  bf16
    u16* aggb = xb + (size_t)N * 64;             // [N*64]  bf16
    u16* hb   = aggb + (size_t)N * 64;           // [N*128] bf16
    u16* m2b  = hb + (size_t)N * 128;            // [N*64]  bf16
    u16* W1c  = m2b + (size_t)N * 64;            // [128*128]
    u16* W2c  = W1c + 128 * 128;                 // [128*128]

    hipMemsetAsync(cnt, 0, (size_t)N * sizeof(int), stream);

    // CSR build.
    count_kernel<<<(E + 255) / 256, 256, 0, stream>>>(dst, cnt, E);
    scan_a_kernel<<<B, 256, 0, stream>>>(cnt, bsum, N);
    scan_b_kernel<<<1, 256, 0, stream>>>(bsum, bOff, off, B, N);
    scan_c_kernel<<<B, 256, 0, stream>>>(cnt, bOff, off, cur, N);
    {
        int chunks = (E + 256 * FILL_EPT - 1) / (256 * FILL_EPT);
        fill_kernel<<<chunks * 8, 256, 0, stream>>>(src, dst, cur, perm, E,
                                                    N8, invN8);
    }

    // bf16 conversions.
    int total4 = N * 64 / 4;
    cvt_kernel<<<(total4 + 255) / 256, 256, 0, stream>>>(x, (u32*)xb, total4);
    prep_w_kernel<<<64, 256, 0, stream>>>(Wl1, Wr1, Wl2, Wr2, W1c, W2c);

    // Phase 1: aggb = bf16(mean of xb over in-edges).
    gather1_kernel<<<(N + 3) / 4, 256, 0, stream>>>((const u32*)xb, perm, off,
                                                    (u32*)aggb, N);
    // Phase 2: hb = bf16(tanh([xb|aggb] @ W1c^T + b1))
    layer1_mfma<<<(N + 63) / 64, 256, 0, stream>>>(xb, aggb, W1c, bl1, hb, N);

    // Phase 3: m2b = bf16(hb @ Wl2^T); r2 = hb @ Wr2^T + b2 -> out
    layer2_mfma<<<(N + 63) / 64, 256, 0, stream>>>(hb, W2c, bl2, m2b, out, N);

    // Phase 4+5: out = log_softmax(mean(m2b) + r2)
    gather2_final_kernel<<<(N + 3) / 4, 256, 0, stream>>>((const u32*)m2b, perm,
                                                          off, out, N);
}

// Round 8
// 255.115 us; speedup vs baseline: 2.3136x; 1.0786x over previous
//
#include <hip/hip_runtime.h>
#include <hip/hip_bf16.h>
#include <math.h>

// N=50000, E=800000, D_IN=64, D_HID=128, D_OUT=64
// Pipeline: CSR build (count / scan / bucketed fill, perm=u16) -> cvt/prep ->
//           gather1(bf16) -> layer1(MFMA) -> layer2(MFMA) -> gather2+logsoftmax.
// R8: fix R7's divergent-shfl tail bug (ds_bpermute reads 0 from exec-masked
//     source lanes) — shfl hoisted out of the divergent if.

typedef unsigned short u16;
typedef unsigned int   u32;
typedef __attribute__((ext_vector_type(8))) __bf16 bf16x8;
typedef __attribute__((ext_vector_type(4))) float  f32x4;

__device__ __forceinline__ u16 f2bf(float f) {            // RNE fp32->bf16
    u32 u = __float_as_uint(f);
    u32 r = (u + 0x7FFFu + ((u >> 16) & 1u)) >> 16;
    return (u16)r;
}
__device__ __forceinline__ float bfl(u32 u) { return __uint_as_float(u << 16); }
__device__ __forceinline__ float bfh(u32 u) { return __uint_as_float(u & 0xFFFF0000u); }

// ---------------------------------------------------------------------------
// CSR build step 1: histogram of dst.
__global__ __launch_bounds__(256) void count_kernel(
    const int* __restrict__ dst, int* __restrict__ cnt, int E)
{
    int e = blockIdx.x * 256 + threadIdx.x;
    if (e < E) atomicAdd(&cnt[dst[e]], 1);
}

__device__ __forceinline__ int wave_incl_scan(int v, int lane)
{
#pragma unroll
    for (int d = 1; d < 64; d <<= 1) {
        int u = __shfl_up(v, d, 64);
        if (lane >= d) v += u;
    }
    return v;
}

// Stage A: per-block chunk sums (1024 elements/block).
__global__ __launch_bounds__(256) void scan_a_kernel(
    const int* __restrict__ cnt, int* __restrict__ bsum, int N)
{
    __shared__ int wsum[4];
    int t = threadIdx.x, lane = t & 63, wv = t >> 6;
    int g0 = blockIdx.x * 1024 + t * 4;
    int s = 0;
#pragma unroll
    for (int j = 0; j < 4; j++) s += (g0 + j < N) ? cnt[g0 + j] : 0;
#pragma unroll
    for (int d = 32; d; d >>= 1) s += __shfl_xor(s, d, 64);
    if (lane == 0) wsum[wv] = s;
    __syncthreads();
    if (t == 0) bsum[blockIdx.x] = wsum[0] + wsum[1] + wsum[2] + wsum[3];
}

// Stage B: single block scans B<=1024 block sums; off[N] = total.
__global__ __launch_bounds__(256) void scan_b_kernel(
    const int* __restrict__ bsum, int* __restrict__ bOff,
    int* __restrict__ off, int B, int N)
{
    __shared__ int wsum[4];
    int t = threadIdx.x, lane = t & 63, wv = t >> 6;
    int v[4];
    int s = 0;
#pragma unroll
    for (int j = 0; j < 4; j++) {
        int i = t * 4 + j;
        v[j] = (i < B) ? bsum[i] : 0;
        s += v[j];
    }
    int incl = wave_incl_scan(s, lane);
    if (lane == 63) wsum[wv] = incl;
    __syncthreads();
    int woff = 0;
    for (int i = 0; i < wv; i++) woff += wsum[i];
    int run = incl - s + woff;
#pragma unroll
    for (int j = 0; j < 4; j++) {
        int i = t * 4 + j;
        if (i < B) bOff[i] = run;
        run += v[j];
    }
    if (t == 255) off[N] = run;
}

// Stage C: per-block exclusive scan + block offset -> off, cur.
__global__ __launch_bounds__(256) void scan_c_kernel(
    const int* __restrict__ cnt, const int* __restrict__ bOff,
    int* __restrict__ off, int* __restrict__ cur, int N)
{
    __shared__ int wsum[4];
    int t = threadIdx.x, lane = t & 63, wv = t >> 6;
    int g0 = blockIdx.x * 1024 + t * 4;
    int v[4];
    int s = 0;
#pragma unroll
    for (int j = 0; j < 4; j++) {
        v[j] = (g0 + j < N) ? cnt[g0 + j] : 0;
        s += v[j];
    }
    int incl = wave_incl_scan(s, lane);
    if (lane == 63) wsum[wv] = incl;
    __syncthreads();
    int woff = 0;
    for (int i = 0; i < wv; i++) woff += wsum[i];
    int run = incl - s + woff + bOff[blockIdx.x];
#pragma unroll
    for (int j = 0; j < 4; j++) {
        if (g0 + j < N) { off[g0 + j] = run; cur[g0 + j] = run; }
        run += v[j];
    }
}

// CSR build step 3: bucketed fill (8 node-buckets; perm u16).
#define FILL_EPT 8   // edges per thread -> 2048 per block
__global__ __launch_bounds__(256) void fill_kernel(
    const int* __restrict__ src, const int* __restrict__ dst,
    int* __restrict__ cur, u16* __restrict__ perm, int E, int N8, float invN8)
{
    int g = blockIdx.x & 7;
    int base = (blockIdx.x >> 3) * (256 * FILL_EPT) + threadIdx.x;
#pragma unroll
    for (int i = 0; i < FILL_EPT; i++) {
        int e = base + i * 256;
        if (e >= E) continue;
        int d = dst[e];
        int b = (int)((float)d * invN8);
        if (d >= (b + 1) * N8) b++;
        else if (d < b * N8) b--;
        if (b != g) continue;
        int pos = atomicAdd(&cur[d], 1);
        perm[pos] = (u16)src[e];
    }
}

// ---------------------------------------------------------------------------
// cvt: x fp32 -> xb bf16, 4 elements/thread.
__global__ __launch_bounds__(256) void cvt_kernel(
    const float* __restrict__ x, u32* __restrict__ xb2, int total4)
{
    int i = blockIdx.x * 256 + threadIdx.x;
    if (i >= total4) return;
    float4 v = ((const float4*)x)[i];
    u32 lo = (u32)f2bf(v.x) | ((u32)f2bf(v.y) << 16);
    u32 hi = (u32)f2bf(v.z) | ((u32)f2bf(v.w) << 16);
    xb2[i * 2]     = lo;
    xb2[i * 2 + 1] = hi;
}

// Weight pack: W1c[o][k] = k<64 ? Wr1[o][k] : Wl1[o][k-64]   (128x128 bf16)
//              W2c[o][k] = o<64 ? Wl2[o][k] : Wr2[o-64][k]   (128x128 bf16)
__global__ __launch_bounds__(256) void prep_w_kernel(
    const float* __restrict__ Wl1, const float* __restrict__ Wr1,
    const float* __restrict__ Wl2, const float* __restrict__ Wr2,
    u16* __restrict__ W1c, u16* __restrict__ W2c)
{
    int i = blockIdx.x * 256 + threadIdx.x;
    if (i >= 128 * 128) return;
    int o = i >> 7, k = i & 127;
    float w1 = (k < 64) ? Wr1[o * 64 + k] : Wl1[o * 64 + (k - 64)];
    W1c[i] = f2bf(w1);
    float w2 = (o < 64) ? Wl2[o * 128 + k] : Wr2[(o - 64) * 128 + k];
    W2c[i] = f2bf(w2);
}

// ---------------------------------------------------------------------------
// Wave gather core: 16 lanes per row (8B = 4 bf16 channels/lane), 4 rows per
// load instruction (quarter = lane>>4), 2x unrolled -> 2 loads in flight.
// NOTE: every __shfl here is executed by ALL 64 lanes (uniform control flow);
// only loads/accumulates are predicated. ds_bpermute returns 0 when the
// SOURCE lane is exec-masked off — a shfl inside a divergent branch is wrong.
__device__ __forceinline__ void gather_core(
    const u32* __restrict__ feat2, const u16* __restrict__ perm,
    int lo, int hi, int lane, int quarter, int c, float acc[4])
{
    float a0 = 0.f, a1 = 0.f, a2 = 0.f, a3 = 0.f;
    float b0 = 0.f, b1 = 0.f, b2 = 0.f, b3 = 0.f;
    for (int base = lo; base < hi; base += 64) {
        int rem = min(64, hi - base);
        int pidx = (lane < rem) ? (int)perm[base + lane] : 0;
        int j = 0;
        for (; j + 8 <= rem; j += 8) {
            int r0 = __shfl(pidx, j + quarter, 64);
            int r1 = __shfl(pidx, j + 4 + quarter, 64);
            uint2 u0 = *(const uint2*)(feat2 + (size_t)r0 * 32 + c * 2);
            uint2 u1 = *(const uint2*)(feat2 + (size_t)r1 * 32 + c * 2);
            a0 += bfl(u0.x); a1 += bfh(u0.x); a2 += bfl(u0.y); a3 += bfh(u0.y);
            b0 += bfl(u1.x); b1 += bfh(u1.x); b2 += bfl(u1.y); b3 += bfh(u1.y);
        }
        for (; j + 4 <= rem; j += 4) {
            int r0 = __shfl(pidx, j + quarter, 64);
            uint2 u0 = *(const uint2*)(feat2 + (size_t)r0 * 32 + c * 2);
            a0 += bfl(u0.x); a1 += bfh(u0.x); a2 += bfl(u0.y); a3 += bfh(u0.y);
        }
        int rr = j + quarter;
        int r0 = __shfl(pidx, rr & 63, 64);   // all lanes execute the shfl
        if (rr < rem) {                        // predicate only the load/add
            uint2 u0 = *(const uint2*)(feat2 + (size_t)r0 * 32 + c * 2);
            a0 += bfl(u0.x); a1 += bfh(u0.x); a2 += bfl(u0.y); a3 += bfh(u0.y);
        }
    }
    acc[0] = a0 + b0; acc[1] = a1 + b1; acc[2] = a2 + b2; acc[3] = a3 + b3;
}

// gather1: aggb[n] = bf16( mean of xb[src] rows ). One wave per node.
__global__ __launch_bounds__(256) void gather1_kernel(
    const u32* __restrict__ xb2, const u16* __restrict__ perm,
    const int* __restrict__ off, u32* __restrict__ aggb2, int N)
{
    int wid  = blockIdx.x * 4 + (threadIdx.x >> 6);
    int lane = threadIdx.x & 63;
    if (wid >= N) return;
    int lo = off[wid], hi = off[wid + 1];
    int quarter = lane >> 4, c = lane & 15;
    float acc[4];
    gather_core(xb2, perm, lo, hi, lane, quarter, c, acc);
#pragma unroll
    for (int i = 0; i < 4; i++) {
        acc[i] += __shfl_xor(acc[i], 16, 64);
        acc[i] += __shfl_xor(acc[i], 32, 64);
    }
    if (quarter == 0) {
        float inv = 1.f / fmaxf((float)(hi - lo), 1.f);
        uint2 p;
        p.x = (u32)f2bf(acc[0] * inv) | ((u32)f2bf(acc[1] * inv) << 16);
        p.y = (u32)f2bf(acc[2] * inv) | ((u32)f2bf(acc[3] * inv) << 16);
        *(uint2*)(aggb2 + (size_t)wid * 32 + c * 2) = p;
    }
}

// ---------------------------------------------------------------------------
// layer1: hb[n] = bf16( tanh( [xb|aggb] @ W1c^T + b1 ) ), MFMA 16x16x32 bf16.
// A frag: A[m=l16][k=quad*8+j]; B frag: B[k=quad*8+j][n=l16] = W[n][quad*8+j].
__global__ __launch_bounds__(256) void layer1_mfma(
    const u16* __restrict__ xb, const u16* __restrict__ aggb,
    const u16* __restrict__ W1, const float* __restrict__ b1,
    u16* __restrict__ hb, int N)
{
    int tid = threadIdx.x;
    int wv = tid >> 6, lane = tid & 63;
    int quad = lane >> 4, l16 = lane & 15;
    int node = blockIdx.x * 64 + wv * 16 + l16;
    int nclamp = min(node, N - 1);
    const u16* xrow = xb   + (size_t)nclamp * 64;
    const u16* arow = aggb + (size_t)nclamp * 64;
    bf16x8 a0 = *(const bf16x8*)(xrow + quad * 8);
    bf16x8 a1 = *(const bf16x8*)(xrow + 32 + quad * 8);
    bf16x8 a2 = *(const bf16x8*)(arow + quad * 8);
    bf16x8 a3 = *(const bf16x8*)(arow + 32 + quad * 8);
    int orow = blockIdx.x * 64 + wv * 16 + quad * 4;   // D rows = nodes
#pragma unroll
    for (int nt = 0; nt < 8; nt++) {
        const u16* wrow = W1 + (size_t)(nt * 16 + l16) * 128 + quad * 8;
        f32x4 acc = {0.f, 0.f, 0.f, 0.f};
        acc = __builtin_amdgcn_mfma_f32_16x16x32_bf16(a0, *(const bf16x8*)(wrow),      acc, 0, 0, 0);
        acc = __builtin_amdgcn_mfma_f32_16x16x32_bf16(a1, *(const bf16x8*)(wrow + 32), acc, 0, 0, 0);
        acc = __builtin_amdgcn_mfma_f32_16x16x32_bf16(a2, *(const bf16x8*)(wrow + 64), acc, 0, 0, 0);
        acc = __builtin_amdgcn_mfma_f32_16x16x32_bf16(a3, *(const bf16x8*)(wrow + 96), acc, 0, 0, 0);
        int oc = nt * 16 + l16;                         // D col = output chan
        float bias = b1[oc];
#pragma unroll
        for (int r = 0; r < 4; r++) {
            int nn = orow + r;
            if (nn < N) hb[(size_t)nn * 128 + oc] = f2bf(tanhf(acc[r] + bias));
        }
    }
}

// layer2: m2b[n] = bf16( hb @ Wl2^T ), r2 (into out) = hb @ Wr2^T + b2.
__global__ __launch_bounds__(256) void layer2_mfma(
    const u16* __restrict__ hb, const u16* __restrict__ W2,
    const float* __restrict__ b2, u16* __restrict__ m2b,
    float* __restrict__ out, int N)
{
    int tid = threadIdx.x;
    int wv = tid >> 6, lane = tid & 63;
    int quad = lane >> 4, l16 = lane & 15;
    int node = blockIdx.x * 64 + wv * 16 + l16;
    int nclamp = min(node, N - 1);
    const u16* hrow = hb + (size_t)nclamp * 128;
    bf16x8 a0 = *(const bf16x8*)(hrow + quad * 8);
    bf16x8 a1 = *(const bf16x8*)(hrow + 32 + quad * 8);
    bf16x8 a2 = *(const bf16x8*)(hrow + 64 + quad * 8);
    bf16x8 a3 = *(const bf16x8*)(hrow + 96 + quad * 8);
    int orow = blockIdx.x * 64 + wv * 16 + quad * 4;
#pragma unroll
    for (int nt = 0; nt < 8; nt++) {
        const u16* wrow = W2 + (size_t)(nt * 16 + l16) * 128 + quad * 8;
        f32x4 acc = {0.f, 0.f, 0.f, 0.f};
        acc = __builtin_amdgcn_mfma_f32_16x16x32_bf16(a0, *(const bf16x8*)(wrow),      acc, 0, 0, 0);
        acc = __builtin_amdgcn_mfma_f32_16x16x32_bf16(a1, *(const bf16x8*)(wrow + 32), acc, 0, 0, 0);
        acc = __builtin_amdgcn_mfma_f32_16x16x32_bf16(a2, *(const bf16x8*)(wrow + 64), acc, 0, 0, 0);
        acc = __builtin_amdgcn_mfma_f32_16x16x32_bf16(a3, *(const bf16x8*)(wrow + 96), acc, 0, 0, 0);
        int oc = nt * 16 + l16;
#pragma unroll
        for (int r = 0; r < 4; r++) {
            int nn = orow + r;
            if (nn >= N) continue;
            if (oc < 64) m2b[(size_t)nn * 64 + oc] = f2bf(acc[r]);
            else         out[(size_t)nn * 64 + (oc - 64)] = acc[r] + b2[oc - 64];
        }
    }
}

// ---------------------------------------------------------------------------
// gather2+final: out[n] = log_softmax( mean(m2b[src]) + r2[n] ). r2 is in out.
__global__ __launch_bounds__(256) void gather2_final_kernel(
    const u32* __restrict__ m2b2, const u16* __restrict__ perm,
    const int* __restrict__ off, float* __restrict__ out, int N)
{
    int wid  = blockIdx.x * 4 + (threadIdx.x >> 6);
    int lane = threadIdx.x & 63;
    if (wid >= N) return;
    int lo = off[wid], hi = off[wid + 1];
    int quarter = lane >> 4, c = lane & 15;
    float acc[4];
    gather_core(m2b2, perm, lo, hi, lane, quarter, c, acc);
#pragma unroll
    for (int i = 0; i < 4; i++) {
        acc[i] += __shfl_xor(acc[i], 16, 64);
        acc[i] += __shfl_xor(acc[i], 32, 64);
    }
    float inv = 1.f / fmaxf((float)(hi - lo), 1.f);
    float4 r2 = ((const float4*)(out + (size_t)wid * 64))[c];
    float v0 = acc[0] * inv + r2.x;
    float v1 = acc[1] * inv + r2.y;
    float v2 = acc[2] * inv + r2.z;
    float v3 = acc[3] * inv + r2.w;
    float m = fmaxf(fmaxf(v0, v1), fmaxf(v2, v3));
#pragma unroll
    for (int o = 1; o < 16; o <<= 1) m = fmaxf(m, __shfl_xor(m, o, 64));
    float sum = expf(v0 - m) + expf(v1 - m) + expf(v2 - m) + expf(v3 - m);
#pragma unroll
    for (int o = 1; o < 16; o <<= 1) sum += __shfl_xor(sum, o, 64);
    if (quarter == 0) {
        float ls = m + logf(sum);
        float4 res = make_float4(v0 - ls, v1 - ls, v2 - ls, v3 - ls);
        ((float4*)(out + (size_t)wid * 64))[c] = res;
    }
}

// ---------------------------------------------------------------------------
extern "C" void kernel_launch(void* const* d_in, const int* in_sizes, int n_in,
                              void* d_out, int out_size, void* d_ws, size_t ws_size,
                              hipStream_t stream)
{
    const float* x   = (const float*)d_in[0];
    const int*   ei  = (const int*)d_in[1];
    const float* Wl1 = (const float*)d_in[2];
    const float* bl1 = (const float*)d_in[3];
    const float* Wr1 = (const float*)d_in[4];
    const float* Wl2 = (const float*)d_in[5];
    const float* bl2 = (const float*)d_in[6];
    const float* Wr2 = (const float*)d_in[7];
    float* out = (float*)d_out;

    int N = in_sizes[0] / 64;   // 50000
    int E = in_sizes[1] / 2;    // 800000
    const int* src = ei;
    const int* dst = ei + E;
    int B = (N + 1023) / 1024;
    int N8 = (N + 7) / 8;
    float invN8 = 1.0f / (float)N8;

    // Workspace layout.
    char* wsb = (char*)d_ws;
    size_t npad = ((size_t)N + 64) & ~(size_t)63;
    int* cnt  = (int*)wsb;                       // [N]
    int* off  = cnt + npad;                      // [N+1]
    int* cur  = off + npad;                      // [N]
    int* bsum = cur + npad;                      // [<=1024]
    int* bOff = bsum + 1024;
    u16* perm = (u16*)(bOff + 1024);             // [E] u16
    size_t epad = ((size_t)E + 63) & ~(size_t)63;
    u16* xb   = perm + epad;                     // [N*64]  bf16
    u16* aggb = xb + (size_t)N * 64;             // [N*64]  bf16
    u16* hb   = aggb + (size_t)N * 64;           // [N*128] bf16
    u16* m2b  = hb + (size_t)N * 128;            // [N*64]  bf16
    u16* W1c  = m2b + (size_t)N * 64;            // [128*128]
    u16* W2c  = W1c + 128 * 128;                 // [128*128]

    hipMemsetAsync(cnt, 0, (size_t)N * sizeof(int), stream);

    // CSR build.
    count_kernel<<<(E + 255) / 256, 256, 0, stream>>>(dst, cnt, E);
    scan_a_kernel<<<B, 256, 0, stream>>>(cnt, bsum, N);
    scan_b_kernel<<<1, 256, 0, stream>>>(bsum, bOff, off, B, N);
    scan_c_kernel<<<B, 256, 0, stream>>>(cnt, bOff, off, cur, N);
    {
        int chunks = (E + 256 * FILL_EPT - 1) / (256 * FILL_EPT);
        fill_kernel<<<chunks * 8, 256, 0, stream>>>(src, dst, cur, perm, E,
                                                    N8, invN8);
    }

    // bf16 conversions.
    int total4 = N * 64 / 4;
    cvt_kernel<<<(total4 + 255) / 256, 256, 0, stream>>>(x, (u32*)xb, total4);
    prep_w_kernel<<<64, 256, 0, stream>>>(Wl1, Wr1, Wl2, Wr2, W1c, W2c);

    // Phase 1: aggb = bf16(mean of xb over in-edges).
    gather1_kernel<<<(N + 3) / 4, 256, 0, stream>>>((const u32*)xb, perm, off,
                                                    (u32*)aggb, N);
    // Phase 2: hb = bf16(tanh([xb|aggb] @ W1c^T + b1))
    layer1_mfma<<<(N + 63) / 64, 256, 0, stream>>>(xb, aggb, W1c, bl1, hb, N);

    // Phase 3: m2b = bf16(hb @ Wl2^T); r2 = hb @ Wr2^T + b2 -> out
    layer2_mfma<<<(N + 63) / 64, 256, 0, stream>>>(hb, W2c, bl2, m2b, out, N);

    // Phase 4+5: out = log_softmax(mean(m2b) + r2)
    gather2_final_kernel<<<(N + 3) / 4, 256, 0, stream>>>((const u32*)m2b, perm,
                                                          off, out, N);
}

// Round 9
// 252.745 us; speedup vs baseline: 2.3353x; 1.0094x over previous
//
#include <hip/hip_runtime.h>
#include <hip/hip_bf16.h>
#include <math.h>

// N=50000, E=800000, D_IN=64, D_HID=128, D_OUT=64
// R9: 9 dispatches: memset, misc(count|cvt|prep), scan_a, scan_c(self-offset),
//     fill(int4), gather1, layer1, layer2, gather2+logsoftmax.

typedef unsigned short u16;
typedef unsigned int   u32;
typedef __attribute__((ext_vector_type(8))) __bf16 bf16x8;
typedef __attribute__((ext_vector_type(4))) float  f32x4;

__device__ __forceinline__ u16 f2bf(float f) {            // RNE fp32->bf16
    u32 u = __float_as_uint(f);
    u32 r = (u + 0x7FFFu + ((u >> 16) & 1u)) >> 16;
    return (u16)r;
}
__device__ __forceinline__ float bfl(u32 u) { return __uint_as_float(u << 16); }
__device__ __forceinline__ float bfh(u32 u) { return __uint_as_float(u & 0xFFFF0000u); }
__device__ __forceinline__ u32 pack2(float a, float b) {
    return (u32)f2bf(a) | ((u32)f2bf(b) << 16);
}

// ---------------------------------------------------------------------------
// Fused misc kernel: blocks [0,CB) count dst histogram (int4, 8 edges/thread);
// blocks [CB,CB+VB) cvt x->bf16 (8 elems/thread); blocks [CB+VB, +64) pack W.
__global__ __launch_bounds__(256) void misc_kernel(
    const int* __restrict__ dst, int* __restrict__ cnt, int E,
    const float* __restrict__ x, uint4* __restrict__ xb4, int nCvt8,
    const float* __restrict__ Wl1, const float* __restrict__ Wr1,
    const float* __restrict__ Wl2, const float* __restrict__ Wr2,
    u16* __restrict__ W1c, u16* __restrict__ W2c, int CB, int VB)
{
    int blk = blockIdx.x, tid = threadIdx.x;
    if (blk < CB) {
        // count: 8 edges per thread via 2x int4.
        int e0 = blk * 2048 + tid * 8;
        if (e0 + 8 <= E) {
            int4 d0 = *(const int4*)(dst + e0);
            int4 d1 = *(const int4*)(dst + e0 + 4);
            atomicAdd(&cnt[d0.x], 1); atomicAdd(&cnt[d0.y], 1);
            atomicAdd(&cnt[d0.z], 1); atomicAdd(&cnt[d0.w], 1);
            atomicAdd(&cnt[d1.x], 1); atomicAdd(&cnt[d1.y], 1);
            atomicAdd(&cnt[d1.z], 1); atomicAdd(&cnt[d1.w], 1);
        } else {
            for (int e = e0; e < E; e++) atomicAdd(&cnt[dst[e]], 1);
        }
    } else if (blk < CB + VB) {
        // cvt: 8 fp32 -> 8 bf16 (one uint4 store) per thread.
        int i = (blk - CB) * 256 + tid;
        if (i < nCvt8) {
            float4 v0 = ((const float4*)x)[i * 2];
            float4 v1 = ((const float4*)x)[i * 2 + 1];
            uint4 p;
            p.x = pack2(v0.x, v0.y); p.y = pack2(v0.z, v0.w);
            p.z = pack2(v1.x, v1.y); p.w = pack2(v1.z, v1.w);
            xb4[i] = p;
        }
    } else {
        // weight pack: W1c[o][k] = k<64 ? Wr1[o][k] : Wl1[o][k-64]
        //              W2c[o][k] = o<64 ? Wl2[o][k] : Wr2[o-64][k]
        int i = (blk - CB - VB) * 256 + tid;
        if (i < 128 * 128) {
            int o = i >> 7, k = i & 127;
            float w1 = (k < 64) ? Wr1[o * 64 + k] : Wl1[o * 64 + (k - 64)];
            W1c[i] = f2bf(w1);
            float w2 = (o < 64) ? Wl2[o * 128 + k] : Wr2[(o - 64) * 128 + k];
            W2c[i] = f2bf(w2);
        }
    }
}

// ---------------------------------------------------------------------------
__device__ __forceinline__ int wave_incl_scan(int v, int lane)
{
#pragma unroll
    for (int d = 1; d < 64; d <<= 1) {
        int u = __shfl_up(v, d, 64);
        if (lane >= d) v += u;
    }
    return v;
}

// Stage A: per-block chunk sums (1024 elements/block).
__global__ __launch_bounds__(256) void scan_a_kernel(
    const int* __restrict__ cnt, int* __restrict__ bsum, int N)
{
    __shared__ int wsum[4];
    int t = threadIdx.x, lane = t & 63, wv = t >> 6;
    int g0 = blockIdx.x * 1024 + t * 4;
    int s = 0;
#pragma unroll
    for (int j = 0; j < 4; j++) s += (g0 + j < N) ? cnt[g0 + j] : 0;
#pragma unroll
    for (int d = 32; d; d >>= 1) s += __shfl_xor(s, d, 64);
    if (lane == 0) wsum[wv] = s;
    __syncthreads();
    if (t == 0) bsum[blockIdx.x] = wsum[0] + wsum[1] + wsum[2] + wsum[3];
}

// Stage C: per-block exclusive scan; block offset computed by summing bsum
// prefix directly (B<=49, uniform scalar loads). Last block writes off[N].
__global__ __launch_bounds__(256) void scan_c_kernel(
    const int* __restrict__ cnt, const int* __restrict__ bsum,
    int* __restrict__ off, int* __restrict__ cur, int N, int B)
{
    __shared__ int wsum[4];
    int t = threadIdx.x, lane = t & 63, wv = t >> 6;
    int boff = 0;
    for (int i = 0; i < blockIdx.x; i++) boff += bsum[i];
    int g0 = blockIdx.x * 1024 + t * 4;
    int v[4];
    int s = 0;
#pragma unroll
    for (int j = 0; j < 4; j++) {
        v[j] = (g0 + j < N) ? cnt[g0 + j] : 0;
        s += v[j];
    }
    int incl = wave_incl_scan(s, lane);
    if (lane == 63) wsum[wv] = incl;
    __syncthreads();
    int woff = 0;
    for (int i = 0; i < wv; i++) woff += wsum[i];
    int run = incl - s + woff + boff;
#pragma unroll
    for (int j = 0; j < 4; j++) {
        if (g0 + j < N) { off[g0 + j] = run; cur[g0 + j] = run; }
        run += v[j];
    }
    if (blockIdx.x == B - 1 && t == 255) off[N] = run;   // total = E
}

// CSR fill: bucketed (8 node-buckets), int4 dst loads, perm u16.
__global__ __launch_bounds__(256) void fill_kernel(
    const int* __restrict__ src, const int* __restrict__ dst,
    int* __restrict__ cur, u16* __restrict__ perm, int E, int N8, float invN8)
{
    int g = blockIdx.x & 7;
    int e0 = (blockIdx.x >> 3) * 2048 + threadIdx.x * 8;
    int d[8];
    bool fast = (e0 + 8 <= E);
    if (fast) {
        int4 d0 = *(const int4*)(dst + e0);
        int4 d1 = *(const int4*)(dst + e0 + 4);
        d[0] = d0.x; d[1] = d0.y; d[2] = d0.z; d[3] = d0.w;
        d[4] = d1.x; d[5] = d1.y; d[6] = d1.z; d[7] = d1.w;
    } else {
        for (int k = 0; k < 8; k++) d[k] = (e0 + k < E) ? dst[e0 + k] : -1;
    }
#pragma unroll
    for (int k = 0; k < 8; k++) {
        int dd = d[k];
        if (dd < 0) continue;
        int b = (int)((float)dd * invN8);
        if (dd >= (b + 1) * N8) b++;
        else if (dd < b * N8) b--;
        if (b != g) continue;
        int pos = atomicAdd(&cur[dd], 1);
        perm[pos] = (u16)src[e0 + k];
    }
}

// ---------------------------------------------------------------------------
// Wave gather core: 16 lanes per row (8B = 4 bf16 channels/lane), 4 rows per
// load instruction (quarter = lane>>4), 2x unrolled -> 2 loads in flight.
// All __shfl executed by ALL 64 lanes; only loads/accumulates predicated.
__device__ __forceinline__ void gather_core(
    const u32* __restrict__ feat2, const u16* __restrict__ perm,
    int lo, int hi, int lane, int quarter, int c, float acc[4])
{
    float a0 = 0.f, a1 = 0.f, a2 = 0.f, a3 = 0.f;
    float b0 = 0.f, b1 = 0.f, b2 = 0.f, b3 = 0.f;
    for (int base = lo; base < hi; base += 64) {
        int rem = min(64, hi - base);
        int pidx = (lane < rem) ? (int)perm[base + lane] : 0;
        int j = 0;
        for (; j + 8 <= rem; j += 8) {
            int r0 = __shfl(pidx, j + quarter, 64);
            int r1 = __shfl(pidx, j + 4 + quarter, 64);
            uint2 u0 = *(const uint2*)(feat2 + (size_t)r0 * 32 + c * 2);
            uint2 u1 = *(const uint2*)(feat2 + (size_t)r1 * 32 + c * 2);
            a0 += bfl(u0.x); a1 += bfh(u0.x); a2 += bfl(u0.y); a3 += bfh(u0.y);
            b0 += bfl(u1.x); b1 += bfh(u1.x); b2 += bfl(u1.y); b3 += bfh(u1.y);
        }
        for (; j + 4 <= rem; j += 4) {
            int r0 = __shfl(pidx, j + quarter, 64);
            uint2 u0 = *(const uint2*)(feat2 + (size_t)r0 * 32 + c * 2);
            a0 += bfl(u0.x); a1 += bfh(u0.x); a2 += bfl(u0.y); a3 += bfh(u0.y);
        }
        int rr = j + quarter;
        int r0 = __shfl(pidx, rr & 63, 64);   // all lanes execute the shfl
        if (rr < rem) {                        // predicate only the load/add
            uint2 u0 = *(const uint2*)(feat2 + (size_t)r0 * 32 + c * 2);
            a0 += bfl(u0.x); a1 += bfh(u0.x); a2 += bfl(u0.y); a3 += bfh(u0.y);
        }
    }
    acc[0] = a0 + b0; acc[1] = a1 + b1; acc[2] = a2 + b2; acc[3] = a3 + b3;
}

// gather1: aggb[n] = bf16( mean of xb[src] rows ). One wave per node.
__global__ __launch_bounds__(256) void gather1_kernel(
    const u32* __restrict__ xb2, const u16* __restrict__ perm,
    const int* __restrict__ off, u32* __restrict__ aggb2, int N)
{
    int wid  = blockIdx.x * 4 + (threadIdx.x >> 6);
    int lane = threadIdx.x & 63;
    if (wid >= N) return;
    int lo = off[wid], hi = off[wid + 1];
    int quarter = lane >> 4, c = lane & 15;
    float acc[4];
    gather_core(xb2, perm, lo, hi, lane, quarter, c, acc);
#pragma unroll
    for (int i = 0; i < 4; i++) {
        acc[i] += __shfl_xor(acc[i], 16, 64);
        acc[i] += __shfl_xor(acc[i], 32, 64);
    }
    if (quarter == 0) {
        float inv = 1.f / fmaxf((float)(hi - lo), 1.f);
        uint2 p;
        p.x = pack2(acc[0] * inv, acc[1] * inv);
        p.y = pack2(acc[2] * inv, acc[3] * inv);
        *(uint2*)(aggb2 + (size_t)wid * 32 + c * 2) = p;
    }
}

// ---------------------------------------------------------------------------
// layer1: hb[n] = bf16( tanh( [xb|aggb] @ W1c^T + b1 ) ), MFMA 16x16x32 bf16.
// A frag: A[m=l16][k=quad*8+j]; B frag: B[k=quad*8+j][n=l16] = W[n][quad*8+j].
__global__ __launch_bounds__(256) void layer1_mfma(
    const u16* __restrict__ xb, const u16* __restrict__ aggb,
    const u16* __restrict__ W1, const float* __restrict__ b1,
    u16* __restrict__ hb, int N)
{
    int tid = threadIdx.x;
    int wv = tid >> 6, lane = tid & 63;
    int quad = lane >> 4, l16 = lane & 15;
    int node = blockIdx.x * 64 + wv * 16 + l16;
    int nclamp = min(node, N - 1);
    const u16* xrow = xb   + (size_t)nclamp * 64;
    const u16* arow = aggb + (size_t)nclamp * 64;
    bf16x8 a0 = *(const bf16x8*)(xrow + quad * 8);
    bf16x8 a1 = *(const bf16x8*)(xrow + 32 + quad * 8);
    bf16x8 a2 = *(const bf16x8*)(arow + quad * 8);
    bf16x8 a3 = *(const bf16x8*)(arow + 32 + quad * 8);
    int orow = blockIdx.x * 64 + wv * 16 + quad * 4;   // D rows = nodes
#pragma unroll
    for (int nt = 0; nt < 8; nt++) {
        const u16* wrow = W1 + (size_t)(nt * 16 + l16) * 128 + quad * 8;
        f32x4 acc = {0.f, 0.f, 0.f, 0.f};
        acc = __builtin_amdgcn_mfma_f32_16x16x32_bf16(a0, *(const bf16x8*)(wrow),      acc, 0, 0, 0);
        acc = __builtin_amdgcn_mfma_f32_16x16x32_bf16(a1, *(const bf16x8*)(wrow + 32), acc, 0, 0, 0);
        acc = __builtin_amdgcn_mfma_f32_16x16x32_bf16(a2, *(const bf16x8*)(wrow + 64), acc, 0, 0, 0);
        acc = __builtin_amdgcn_mfma_f32_16x16x32_bf16(a3, *(const bf16x8*)(wrow + 96), acc, 0, 0, 0);
        int oc = nt * 16 + l16;                         // D col = output chan
        float bias = b1[oc];
#pragma unroll
        for (int r = 0; r < 4; r++) {
            int nn = orow + r;
            if (nn < N) hb[(size_t)nn * 128 + oc] = f2bf(tanhf(acc[r] + bias));
        }
    }
}

// layer2: m2b[n] = bf16( hb @ Wl2^T ), r2 (into out) = hb @ Wr2^T + b2.
__global__ __launch_bounds__(256) void layer2_mfma(
    const u16* __restrict__ hb, const u16* __restrict__ W2,
    const float* __restrict__ b2, u16* __restrict__ m2b,
    float* __restrict__ out, int N)
{
    int tid = threadIdx.x;
    int wv = tid >> 6, lane = tid & 63;
    int quad = lane >> 4, l16 = lane & 15;
    int node = blockIdx.x * 64 + wv * 16 + l16;
    int nclamp = min(node, N - 1);
    const u16* hrow = hb + (size_t)nclamp * 128;
    bf16x8 a0 = *(const bf16x8*)(hrow + quad * 8);
    bf16x8 a1 = *(const bf16x8*)(hrow + 32 + quad * 8);
    bf16x8 a2 = *(const bf16x8*)(hrow + 64 + quad * 8);
    bf16x8 a3 = *(const bf16x8*)(hrow + 96 + quad * 8);
    int orow = blockIdx.x * 64 + wv * 16 + quad * 4;
#pragma unroll
    for (int nt = 0; nt < 8; nt++) {
        const u16* wrow = W2 + (size_t)(nt * 16 + l16) * 128 + quad * 8;
        f32x4 acc = {0.f, 0.f, 0.f, 0.f};
        acc = __builtin_amdgcn_mfma_f32_16x16x32_bf16(a0, *(const bf16x8*)(wrow),      acc, 0, 0, 0);
        acc = __builtin_amdgcn_mfma_f32_16x16x32_bf16(a1, *(const bf16x8*)(wrow + 32), acc, 0, 0, 0);
        acc = __builtin_amdgcn_mfma_f32_16x16x32_bf16(a2, *(const bf16x8*)(wrow + 64), acc, 0, 0, 0);
        acc = __builtin_amdgcn_mfma_f32_16x16x32_bf16(a3, *(const bf16x8*)(wrow + 96), acc, 0, 0, 0);
        int oc = nt * 16 + l16;
#pragma unroll
        for (int r = 0; r < 4; r++) {
            int nn = orow + r;
            if (nn >= N) continue;
            if (oc < 64) m2b[(size_t)nn * 64 + oc] = f2bf(acc[r]);
            else         out[(size_t)nn * 64 + (oc - 64)] = acc[r] + b2[oc - 64];
        }
    }
}

// ---------------------------------------------------------------------------
// gather2+final: out[n] = log_softmax( mean(m2b[src]) + r2[n] ). r2 is in out.
__global__ __launch_bounds__(256) void gather2_final_kernel(
    const u32* __restrict__ m2b2, const u16* __restrict__ perm,
    const int* __restrict__ off, float* __restrict__ out, int N)
{
    int wid  = blockIdx.x * 4 + (threadIdx.x >> 6);
    int lane = threadIdx.x & 63;
    if (wid >= N) return;
    int lo = off[wid], hi = off[wid + 1];
    int quarter = lane >> 4, c = lane & 15;
    float acc[4];
    gather_core(m2b2, perm, lo, hi, lane, quarter, c, acc);
#pragma unroll
    for (int i = 0; i < 4; i++) {
        acc[i] += __shfl_xor(acc[i], 16, 64);
        acc[i] += __shfl_xor(acc[i], 32, 64);
    }
    float inv = 1.f / fmaxf((float)(hi - lo), 1.f);
    float4 r2 = ((const float4*)(out + (size_t)wid * 64))[c];
    float v0 = acc[0] * inv + r2.x;
    float v1 = acc[1] * inv + r2.y;
    float v2 = acc[2] * inv + r2.z;
    float v3 = acc[3] * inv + r2.w;
    float m = fmaxf(fmaxf(v0, v1), fmaxf(v2, v3));
#pragma unroll
    for (int o = 1; o < 16; o <<= 1) m = fmaxf(m, __shfl_xor(m, o, 64));
    float sum = expf(v0 - m) + expf(v1 - m) + expf(v2 - m) + expf(v3 - m);
#pragma unroll
    for (int o = 1; o < 16; o <<= 1) sum += __shfl_xor(sum, o, 64);
    if (quarter == 0) {
        float ls = m + logf(sum);
        float4 res = make_float4(v0 - ls, v1 - ls, v2 - ls, v3 - ls);
        ((float4*)(out + (size_t)wid * 64))[c] = res;
    }
}

// ---------------------------------------------------------------------------
extern "C" void kernel_launch(void* const* d_in, const int* in_sizes, int n_in,
                              void* d_out, int out_size, void* d_ws, size_t ws_size,
                              hipStream_t stream)
{
    const float* x   = (const float*)d_in[0];
    const int*   ei  = (const int*)d_in[1];
    const float* Wl1 = (const float*)d_in[2];
    const float* bl1 = (const float*)d_in[3];
    const float* Wr1 = (const float*)d_in[4];
    const float* Wl2 = (const float*)d_in[5];
    const float* bl2 = (const float*)d_in[6];
    const float* Wr2 = (const float*)d_in[7];
    float* out = (float*)d_out;

    int N = in_sizes[0] / 64;   // 50000
    int E = in_sizes[1] / 2;    // 800000
    const int* src = ei;
    const int* dst = ei + E;
    int B = (N + 1023) / 1024;
    int N8 = (N + 7) / 8;
    float invN8 = 1.0f / (float)N8;

    // Workspace layout.
    char* wsb = (char*)d_ws;
    size_t npad = ((size_t)N + 64) & ~(size_t)63;
    int* cnt  = (int*)wsb;                       // [N]
    int* off  = cnt + npad;                      // [N+1]
    int* cur  = off + npad;                      // [N]
    int* bsum = cur + npad;                      // [<=1024]
    int* bOff = bsum + 1024;                     // (unused, keeps layout)
    u16* perm = (u16*)(bOff + 1024);             // [E] u16
    size_t epad = ((size_t)E + 63) & ~(size_t)63;
    u16* xb   = perm + epad;                     // [N*64]  bf16
    u16* aggb = xb + (size_t)N * 64;             // [N*64]  bf16
    u16* hb   = aggb + (size_t)N * 64;           // [N*128] bf16
    u16* m2b  = hb + (size_t)N * 128;            // [N*64]  bf16
    u16* W1c  = m2b + (size_t)N * 64;            // [128*128]
    u16* W2c  = W1c + 128 * 128;                 // [128*128]

    hipMemsetAsync(cnt, 0, (size_t)N * sizeof(int), stream);

    // Fused count | cvt | prep.
    int CB = (E + 2047) / 2048;                  // count blocks (8 edges/thr)
    int nCvt8 = N * 64 / 8;                      // 8 elems/thread
    int VB = (nCvt8 + 255) / 256;
    misc_kernel<<<CB + VB + 64, 256, 0, stream>>>(
        dst, cnt, E, x, (uint4*)xb, nCvt8,
        Wl1, Wr1, Wl2, Wr2, W1c, W2c, CB, VB);

    // Scan (2 stages) + fill.
    scan_a_kernel<<<B, 256, 0, stream>>>(cnt, bsum, N);
    scan_c_kernel<<<B, 256, 0, stream>>>(cnt, bsum, off, cur, N, B);
    {
        int chunks = (E + 2047) / 2048;
        fill_kernel<<<chunks * 8, 256, 0, stream>>>(src, dst, cur, perm, E,
                                                    N8, invN8);
    }

    // Phase 1: aggb = bf16(mean of xb over in-edges).
    gather1_kernel<<<(N + 3) / 4, 256, 0, stream>>>((const u32*)xb, perm, off,
                                                    (u32*)aggb, N);
    // Phase 2: hb = bf16(tanh([xb|aggb] @ W1c^T + b1))
    layer1_mfma<<<(N + 63) / 64, 256, 0, stream>>>(xb, aggb, W1c, bl1, hb, N);

    // Phase 3: m2b = bf16(hb @ Wl2^T); r2 = hb @ Wr2^T + b2 -> out
    layer2_mfma<<<(N + 63) / 64, 256, 0, stream>>>(hb, W2c, bl2, m2b, out, N);

    // Phase 4+5: out = log_softmax(mean(m2b) + r2)
    gather2_final_kernel<<<(N + 3) / 4, 256, 0, stream>>>((const u32*)m2b, perm,
                                                          off, out, N);
}